// Round 5
// baseline (1500.839 us; speedup 1.0000x reference)
//
#include <hip/hip_runtime.h>
#include <stdint.h>

namespace {

constexpr int NN   = 100000;    // nodes per graph
constexpr int NEDG = 1600000;   // edges per graph
constexpr int NBAT = 512;       // graphs per batch
constexpr int NSEG = 33;        // piecewise-linear segments of edge MLP (32 breakpoints)
constexpr int EBLK = NEDG / 256;  // 6250 blocks per graph for edge kernels

// table layout (floats): bp[32] | d1[NSEG*32] | c1[NSEG*32] | per-enc {d2[NSEG*64], c2[NSEG*64]} x2
constexpr int TAB_BP = 0;
constexpr int TAB_D1 = 32;
constexpr int TAB_C1 = TAB_D1 + NSEG * 32;
constexpr int TAB_E2 = TAB_C1 + NSEG * 32;
constexpr int TAB_TOTAL = TAB_E2 + 4 * NSEG * 64;

__device__ __forceinline__ float relu_(float x) { return fmaxf(x, 0.0f); }

__device__ __forceinline__ float4 shfl_xor4(float4 v, int m) {
  return make_float4(__shfl_xor(v.x, m), __shfl_xor(v.y, m),
                     __shfl_xor(v.z, m), __shfl_xor(v.w, m));
}

// ---------------------------------------------------------------------------
// Precompute piecewise-linear tables for e(a) = relu(a*W1+b1)@W2+b2 and the
// folded e2(a) = e(a)@linW + linb. Exact reassociation of the reference math.
// ---------------------------------------------------------------------------
__global__ void build_tables(const float* __restrict__ eW1, const float* __restrict__ eb1,
                             const float* __restrict__ eW2, const float* __restrict__ eb2,
                             const float* __restrict__ sLW, const float* __restrict__ sLb,
                             const float* __restrict__ gLW, const float* __restrict__ gLb,
                             float* __restrict__ tabs) {
  __shared__ float traw[32];
  __shared__ float ts[32];
  __shared__ float dt[NSEG * 32];
  __shared__ float ct[NSEG * 32];
  int tid = threadIdx.x;
  if (tid < 32) {
    float w = eW1[tid], b = eb1[tid];
    traw[tid] = (w != 0.0f) ? (-b / w) : 3.0e38f;
  }
  __syncthreads();
  if (tid < 32) {  // rank sort (stable for duplicates)
    float v = traw[tid];
    int r = 0;
    for (int j = 0; j < 32; ++j) {
      float u = traw[j];
      r += (u < v) || (u == v && j < tid);
    }
    ts[r] = v;
  }
  __syncthreads();
  if (tid < 32) tabs[TAB_BP + tid] = ts[tid];
  for (int idx = tid; idx < NSEG * 32; idx += blockDim.x) {
    int s = idx >> 5, j = idx & 31;
    float a;  // representative point strictly inside segment s: (ts[s-1], ts[s]]
    if (s == 0)            a = ts[0] - 1.0f;
    else if (s == NSEG - 1) a = ts[31] + 1.0f;
    else                   a = 0.5f * ts[s - 1] + 0.5f * ts[s];
    float d = 0.0f, c = 0.0f;
    for (int i = 0; i < 32; ++i) {
      float w = eW1[i], b = eb1[i];
      if (fmaf(a, w, b) > 0.0f) {
        float w2 = eW2[i * 32 + j];
        d = fmaf(w, w2, d);
        c = fmaf(b, w2, c);
      }
    }
    c += eb2[j];
    dt[idx] = d; ct[idx] = c;
    tabs[TAB_D1 + idx] = d;
    tabs[TAB_C1 + idx] = c;
  }
  __syncthreads();
  for (int idx = tid; idx < NSEG * 64; idx += blockDim.x) {
    int s = idx >> 6, k = idx & 63;
    float ds = 0.f, cs = 0.f, dg = 0.f, cg = 0.f;
    for (int j = 0; j < 32; ++j) {
      float dv = dt[s * 32 + j], cv = ct[s * 32 + j];
      float ws = sLW[j * 64 + k], wg = gLW[j * 64 + k];
      ds = fmaf(dv, ws, ds); cs = fmaf(cv, ws, cs);
      dg = fmaf(dv, wg, dg); cg = fmaf(cv, wg, cg);
    }
    cs += sLb[k]; cg += gLb[k];
    tabs[TAB_E2 + idx]                 = ds;
    tabs[TAB_E2 + NSEG * 64 + idx]     = cs;
    tabs[TAB_E2 + 2 * NSEG * 64 + idx] = dg;
    tabs[TAB_E2 + 3 * NSEG * 64 + idx] = cg;
  }
}

// ---------------------------------------------------------------------------
// x0[n,32] = MLP2(clip((names+2)/SCALE,0,1))
// ---------------------------------------------------------------------------
__global__ __launch_bounds__(256, 2) void node_embed(
    const int* __restrict__ names,
    const float* __restrict__ W1, const float* __restrict__ b1,
    const float* __restrict__ W2, const float* __restrict__ b2,
    float* __restrict__ x0) {
  int n = blockIdx.x * 256 + threadIdx.x;
  if (n >= NN) return;
  float norm = ((float)names[n] + 2.0f) / 281474976710655.0f;
  norm = fminf(fmaxf(norm, 0.0f), 1.0f);
  float h[32];
#pragma unroll
  for (int i = 0; i < 32; ++i) h[i] = relu_(fmaf(norm, W1[i], b1[i]));
  float4* out = (float4*)(x0 + (size_t)n * 32);
  for (int j0 = 0; j0 < 32; j0 += 4) {
    float a0 = b2[j0], a1 = b2[j0 + 1], a2 = b2[j0 + 2], a3 = b2[j0 + 3];
#pragma unroll
    for (int i = 0; i < 32; ++i) {
      float hv = h[i];
      a0 = fmaf(hv, W2[i * 32 + j0],     a0);
      a1 = fmaf(hv, W2[i * 32 + j0 + 1], a1);
      a2 = fmaf(hv, W2[i * 32 + j0 + 2], a2);
      a3 = fmaf(hv, W2[i * 32 + j0 + 3], a3);
    }
    out[j0 >> 2] = make_float4(a0, a1, a2, a3);
  }
}

// ---------------------------------------------------------------------------
// Dual-graph CSR-by-dst build (merged: one latency-bound pass, 2x atomics in
// flight). Graph-g node bins offset by NN. Blocks [0,EBLK)->s, rest->g.
// ---------------------------------------------------------------------------
__global__ __launch_bounds__(256) void hist_dst_dual(
    const int* __restrict__ dst_s, const int* __restrict__ dst_g,
    int* __restrict__ cnt) {
  int half = blockIdx.x >= EBLK;
  int e = (blockIdx.x - half * EBLK) * 256 + threadIdx.x;  // exact
  int d = half ? (dst_g[e] + NN) : dst_s[e];
  atomicAdd(&cnt[d], 1);
}

__global__ __launch_bounds__(256) void block_sums(const int* __restrict__ cnt, int* __restrict__ bsum, int n) {
  __shared__ int s[256];
  int i = blockIdx.x * 256 + threadIdx.x;
  s[threadIdx.x] = (i < n) ? cnt[i] : 0;
  __syncthreads();
  for (int st = 128; st > 0; st >>= 1) {
    if ((int)threadIdx.x < st) s[threadIdx.x] += s[threadIdx.x + st];
    __syncthreads();
  }
  if (threadIdx.x == 0) bsum[blockIdx.x] = s[0];
}

__global__ __launch_bounds__(1024) void scan_partials(int* __restrict__ bsum, int nb) {
  __shared__ int s[1024];
  int v = ((int)threadIdx.x < nb) ? bsum[threadIdx.x] : 0;
  s[threadIdx.x] = v;
  __syncthreads();
  for (int st = 1; st < 1024; st <<= 1) {
    int t = ((int)threadIdx.x >= st) ? s[threadIdx.x - st] : 0;
    __syncthreads();
    s[threadIdx.x] += t;
    __syncthreads();
  }
  if ((int)threadIdx.x < nb) bsum[threadIdx.x] = s[threadIdx.x] - v;  // exclusive
}

__global__ __launch_bounds__(256) void write_rowptr(
    const int* __restrict__ cnt, const int* __restrict__ bsum,
    int* __restrict__ rowptr, int* __restrict__ wp, int n, int total) {
  __shared__ int s[256];
  int i = blockIdx.x * 256 + threadIdx.x;
  int v = (i < n) ? cnt[i] : 0;
  s[threadIdx.x] = v;
  __syncthreads();
  for (int st = 1; st < 256; st <<= 1) {
    int t = ((int)threadIdx.x >= st) ? s[threadIdx.x - st] : 0;
    __syncthreads();
    s[threadIdx.x] += t;
    __syncthreads();
  }
  int excl = s[threadIdx.x] - v + bsum[blockIdx.x];
  if (i < n) { rowptr[i] = excl; wp[i] = excl; }
  if (i == n - 1) rowptr[n] = total;
}

// 1 edge/thread (4/thread regressed round 3). Breakpoints staged in LDS;
// unrolled 32-compare replaces the dependent global binary search.
__global__ __launch_bounds__(256) void csr_fill_dual(
    const int* __restrict__ src_s, const int* __restrict__ dst_s, const float* __restrict__ attr_s,
    const int* __restrict__ src_g, const int* __restrict__ dst_g, const float* __restrict__ attr_g,
    const float* __restrict__ tabs, int* __restrict__ wp, int2* __restrict__ colattr) {
  __shared__ float bp[32];
  if (threadIdx.x < 32) bp[threadIdx.x] = tabs[TAB_BP + threadIdx.x];
  __syncthreads();
  int half = blockIdx.x >= EBLK;
  int e = (blockIdx.x - half * EBLK) * 256 + threadIdx.x;  // exact
  int sl, d;
  float a;
  if (half) { sl = src_g[e]; d = dst_g[e] + NN; a = attr_g[e]; }
  else      { sl = src_s[e]; d = dst_s[e];      a = attr_s[e]; }
  int g = 0;  // seg = #(bp < a)
#pragma unroll
  for (int i = 0; i < 32; ++i) g += (bp[i] < a);
  int pos = atomicAdd(&wp[d], 1);
  colattr[pos] = make_int2(sl | (g << 20), __float_as_int(a));  // src<2^17, seg<64
}

// ---------------------------------------------------------------------------
// GINE aggregation, dst-major. One WAVE per node; wave processes several
// edges concurrently (sub = edge slot, fq = float4 feature chunk) so 8-16 row
// gathers are in flight per wave. hb[n] = x[n] + sum_j relu(x[src_j] + e_j)
// ---------------------------------------------------------------------------
__global__ __launch_bounds__(256) void conv1_agg(
    const float* __restrict__ x0, const int* __restrict__ rowptr,
    const int2* __restrict__ colattr, const float* __restrict__ tabs,
    float* __restrict__ hb) {
  __shared__ float dt[NSEG * 32];
  __shared__ float ct[NSEG * 32];
  for (int i = threadIdx.x; i < NSEG * 32; i += 256) {
    dt[i] = tabs[TAB_D1 + i];
    ct[i] = tabs[TAB_C1 + i];
  }
  __syncthreads();
  int n = blockIdx.x * 4 + (threadIdx.x >> 6);  // grid exact: NN/4
  int lane = threadIdx.x & 63;
  int sub = lane & 7;        // 8 edges in flight (x2 unroll = 16)
  int fq  = lane >> 3;       // 8 float4 chunks -> 32 features
  int f0  = fq * 4;
  int beg = rowptr[n], end = rowptr[n + 1];
  float4 acc = make_float4(0.f, 0.f, 0.f, 0.f);
  for (int k = beg + sub; k < end; k += 16) {
    int2 ca0 = colattr[k];
    int kb = k + 8;
    bool h1 = kb < end;
    int2 ca1 = h1 ? colattr[kb] : ca0;
    unsigned p0 = (unsigned)ca0.x, p1 = (unsigned)ca1.x;
    int s0 = (int)(p0 & 0xFFFFFu), g0 = (int)(p0 >> 20);
    int s1 = (int)(p1 & 0xFFFFFu), g1 = (int)(p1 >> 20);
    float a0 = __int_as_float(ca0.y), a1 = __int_as_float(ca1.y);
    float4 xv0 = *(const float4*)(x0 + (size_t)s0 * 32 + f0);
    float4 xv1 = *(const float4*)(x0 + (size_t)s1 * 32 + f0);
    float4 d0 = *(const float4*)&dt[g0 * 32 + f0];
    float4 c0 = *(const float4*)&ct[g0 * 32 + f0];
    float4 d1 = *(const float4*)&dt[g1 * 32 + f0];
    float4 c1 = *(const float4*)&ct[g1 * 32 + f0];
    acc.x += relu_(xv0.x + fmaf(a0, d0.x, c0.x));
    acc.y += relu_(xv0.y + fmaf(a0, d0.y, c0.y));
    acc.z += relu_(xv0.z + fmaf(a0, d0.z, c0.z));
    acc.w += relu_(xv0.w + fmaf(a0, d0.w, c0.w));
    if (h1) {
      acc.x += relu_(xv1.x + fmaf(a1, d1.x, c1.x));
      acc.y += relu_(xv1.y + fmaf(a1, d1.y, c1.y));
      acc.z += relu_(xv1.z + fmaf(a1, d1.z, c1.z));
      acc.w += relu_(xv1.w + fmaf(a1, d1.w, c1.w));
    }
  }
#pragma unroll
  for (int m = 1; m < 8; m <<= 1) {
    float4 o = shfl_xor4(acc, m);
    acc.x += o.x; acc.y += o.y; acc.z += o.z; acc.w += o.w;
  }
  if (sub == 0) {
    const float4 self = *(const float4*)(x0 + (size_t)n * 32 + f0);
    *(float4*)(hb + (size_t)n * 32 + f0) =
        make_float4(self.x + acc.x, self.y + acc.y, self.z + acc.z, self.w + acc.w);
  }
}

__global__ __launch_bounds__(256) void conv2_agg(
    const float* __restrict__ x1, const int* __restrict__ rowptr,
    const int2* __restrict__ colattr, const float* __restrict__ tabs, int enc,
    float* __restrict__ hb) {
  __shared__ float dt[NSEG * 64];
  __shared__ float ct[NSEG * 64];
  const float* d2 = tabs + TAB_E2 + (size_t)enc * 2 * NSEG * 64;
  for (int i = threadIdx.x; i < NSEG * 64; i += 256) {
    dt[i] = d2[i];
    ct[i] = d2[NSEG * 64 + i];
  }
  __syncthreads();
  int n = blockIdx.x * 4 + (threadIdx.x >> 6);  // grid exact: NN/4
  int lane = threadIdx.x & 63;
  int sub = lane & 3;        // 4 edges in flight (x2 unroll = 8)
  int fq  = lane >> 2;       // 16 float4 chunks -> 64 features
  int f0  = fq * 4;
  int beg = rowptr[n], end = rowptr[n + 1];
  float4 acc = make_float4(0.f, 0.f, 0.f, 0.f);
  for (int k = beg + sub; k < end; k += 8) {
    int2 ca0 = colattr[k];
    int kb = k + 4;
    bool h1 = kb < end;
    int2 ca1 = h1 ? colattr[kb] : ca0;
    unsigned p0 = (unsigned)ca0.x, p1 = (unsigned)ca1.x;
    int s0 = (int)(p0 & 0xFFFFFu), g0 = (int)(p0 >> 20);
    int s1 = (int)(p1 & 0xFFFFFu), g1 = (int)(p1 >> 20);
    float a0 = __int_as_float(ca0.y), a1 = __int_as_float(ca1.y);
    float4 xv0 = *(const float4*)(x1 + (size_t)s0 * 64 + f0);
    float4 xv1 = *(const float4*)(x1 + (size_t)s1 * 64 + f0);
    float4 d0 = *(const float4*)&dt[g0 * 64 + f0];
    float4 c0 = *(const float4*)&ct[g0 * 64 + f0];
    float4 d1 = *(const float4*)&dt[g1 * 64 + f0];
    float4 c1 = *(const float4*)&ct[g1 * 64 + f0];
    acc.x += relu_(xv0.x + fmaf(a0, d0.x, c0.x));
    acc.y += relu_(xv0.y + fmaf(a0, d0.y, c0.y));
    acc.z += relu_(xv0.z + fmaf(a0, d0.z, c0.z));
    acc.w += relu_(xv0.w + fmaf(a0, d0.w, c0.w));
    if (h1) {
      acc.x += relu_(xv1.x + fmaf(a1, d1.x, c1.x));
      acc.y += relu_(xv1.y + fmaf(a1, d1.y, c1.y));
      acc.z += relu_(xv1.z + fmaf(a1, d1.z, c1.z));
      acc.w += relu_(xv1.w + fmaf(a1, d1.w, c1.w));
    }
  }
#pragma unroll
  for (int m = 1; m < 4; m <<= 1) {
    float4 o = shfl_xor4(acc, m);
    acc.x += o.x; acc.y += o.y; acc.z += o.z; acc.w += o.w;
  }
  if (sub == 0) {
    const float4 self = *(const float4*)(x1 + (size_t)n * 64 + f0);
    *(float4*)(hb + (size_t)n * 64 + f0) =
        make_float4(self.x + acc.x, self.y + acc.y, self.z + acc.z, self.w + acc.w);
  }
}

// ---------------------------------------------------------------------------
// Per-node MLP2 (IN -> 64 -> 64), relu on both (conv wrapper relu on output).
// 16 lanes per node, each lane owns a float4 feature quad -> max ~32 VGPRs,
// NO 64-element register array (round-3/4 showed the compiler spills y[64]
// to scratch at its default 52-VGPR occupancy target regardless of
// __launch_bounds__). Layer-1 output round-trips through bank-padded LDS:
// ys[64][17] -> writes are 2-way bank aliased (free), reads broadcast.
// Weights are wave-dedup'd float4 global loads (W1/W2 = 16 KB, L1-resident).
// ---------------------------------------------------------------------------
template <int IN>
__global__ __launch_bounds__(256) void node_mlp16(
    const float* __restrict__ hin,
    const float* __restrict__ W1, const float* __restrict__ b1,
    const float* __restrict__ W2, const float* __restrict__ b2,
    float* __restrict__ xout) {
  constexpr int LOG = (IN == 32) ? 5 : 6;
  __shared__ float hs[16][IN + 1];
  __shared__ float ys[64][17];
  int base = blockIdx.x * 16;  // grid exact: NN/16 = 6250
  for (int i = threadIdx.x; i < 16 * IN; i += 256) {
    int ln = i >> LOG, k = i & (IN - 1);
    hs[ln][k] = hin[(size_t)(base + ln) * IN + k];
  }
  __syncthreads();
  int g = threadIdx.x >> 4;   // node within tile [0,16)
  int j = threadIdx.x & 15;   // feature quad [0,16)
  int f0 = j * 4;
  float a0, a1, a2, a3;
  {
    const float4 b = *(const float4*)(b1 + f0);
    a0 = b.x; a1 = b.y; a2 = b.z; a3 = b.w;
  }
  for (int k = 0; k < IN; ++k) {
    float hv = hs[g][k];
    const float4 w = *(const float4*)(W1 + k * 64 + f0);
    a0 = fmaf(hv, w.x, a0); a1 = fmaf(hv, w.y, a1);
    a2 = fmaf(hv, w.z, a2); a3 = fmaf(hv, w.w, a3);
  }
  ys[f0 + 0][g] = relu_(a0);
  ys[f0 + 1][g] = relu_(a1);
  ys[f0 + 2][g] = relu_(a2);
  ys[f0 + 3][g] = relu_(a3);
  __syncthreads();
  {
    const float4 b = *(const float4*)(b2 + f0);
    a0 = b.x; a1 = b.y; a2 = b.z; a3 = b.w;
  }
  for (int k = 0; k < 64; ++k) {
    float yv = ys[k][g];
    const float4 w = *(const float4*)(W2 + k * 64 + f0);
    a0 = fmaf(yv, w.x, a0); a1 = fmaf(yv, w.y, a1);
    a2 = fmaf(yv, w.z, a2); a3 = fmaf(yv, w.w, a3);
  }
  *(float4*)(xout + (size_t)(base + g) * 64 + f0) =
      make_float4(relu_(a0), relu_(a1), relu_(a2), relu_(a3));
}

// ---------------------------------------------------------------------------
// global mean pool (batch is sorted -> contiguous node ranges per graph)
// ---------------------------------------------------------------------------
__global__ __launch_bounds__(256) void hist_batch(const int* __restrict__ bat, int* __restrict__ bcnt) {
  int i = blockIdx.x * 256 + threadIdx.x;
  if (i < NN) atomicAdd(&bcnt[bat[i]], 1);
}

__global__ __launch_bounds__(512) void batch_rowptr(const int* __restrict__ bcnt, int* __restrict__ brow) {
  __shared__ int s[512];
  int v = bcnt[threadIdx.x];
  s[threadIdx.x] = v;
  __syncthreads();
  for (int st = 1; st < 512; st <<= 1) {
    int t = ((int)threadIdx.x >= st) ? s[threadIdx.x - st] : 0;
    __syncthreads();
    s[threadIdx.x] += t;
    __syncthreads();
  }
  if (threadIdx.x == 0) brow[0] = 0;
  brow[threadIdx.x + 1] = s[threadIdx.x];
}

__global__ __launch_bounds__(256) void pool_mean(
    const float* __restrict__ x2, const int* __restrict__ brow, float* __restrict__ pool) {
  __shared__ float s[4][64];
  int g = blockIdx.x;
  int f = threadIdx.x & 63, c = threadIdx.x >> 6;
  int beg = brow[g], end = brow[g + 1];
  float acc = 0.0f;
  for (int n = beg + c; n < end; n += 4) acc += x2[(size_t)n * 64 + f];
  s[c][f] = acc;
  __syncthreads();
  if (c == 0) {
    float tot = s[0][f] + s[1][f] + s[2][f] + s[3][f];
    float m = (float)(end - beg);
    pool[g * 64 + f] = tot / fmaxf(m, 1.0f);
  }
}

// ---------------------------------------------------------------------------
// regressor: out[b] = relu([s|g|depth] @ rW1 + rb1) @ rW2 + rb2
// Same 16-lane-per-row structure as node_mlp16 (no register arrays).
// ---------------------------------------------------------------------------
__global__ __launch_bounds__(256) void regressor16(
    const float* __restrict__ ps, const float* __restrict__ pg, const float* __restrict__ depth,
    const float* __restrict__ W1, const float* __restrict__ b1,
    const float* __restrict__ W2, const float* __restrict__ b2,
    float* __restrict__ out) {
  __shared__ float zs[16][132];   // [row][k], k in [0,129)
  __shared__ float ys[64][17];
  int base = blockIdx.x * 16;     // grid 32 blocks x 16 rows = 512 exact
  for (int i = threadIdx.x; i < 16 * 64; i += 256) {
    int ln = i >> 6, k = i & 63;
    zs[ln][k]      = ps[(size_t)(base + ln) * 64 + k];
    zs[ln][64 + k] = pg[(size_t)(base + ln) * 64 + k];
  }
  if (threadIdx.x < 16) zs[threadIdx.x][128] = depth[base + threadIdx.x];
  __syncthreads();
  int g = threadIdx.x >> 4;
  int j = threadIdx.x & 15;
  int f0 = j * 4;
  float a0, a1, a2, a3;
  {
    const float4 b = *(const float4*)(b1 + f0);
    a0 = b.x; a1 = b.y; a2 = b.z; a3 = b.w;
  }
  for (int k = 0; k < 129; ++k) {
    float zv = zs[g][k];
    const float4 w = *(const float4*)(W1 + k * 64 + f0);
    a0 = fmaf(zv, w.x, a0); a1 = fmaf(zv, w.y, a1);
    a2 = fmaf(zv, w.z, a2); a3 = fmaf(zv, w.w, a3);
  }
  ys[f0 + 0][g] = relu_(a0);
  ys[f0 + 1][g] = relu_(a1);
  ys[f0 + 2][g] = relu_(a2);
  ys[f0 + 3][g] = relu_(a3);
  __syncthreads();
  // layer 2: scalar output, partial dot over this lane's 4 features
  float s = ys[f0 + 0][g] * W2[f0 + 0] + ys[f0 + 1][g] * W2[f0 + 1] +
            ys[f0 + 2][g] * W2[f0 + 2] + ys[f0 + 3][g] * W2[f0 + 3];
#pragma unroll
  for (int m = 1; m < 16; m <<= 1) s += __shfl_xor(s, m);
  if (j == 0) out[base + g] = s + b2[0];
}

}  // namespace

extern "C" void kernel_launch(void* const* d_in, const int* in_sizes, int n_in,
                              void* d_out, int out_size, void* d_ws, size_t ws_size,
                              hipStream_t stream) {
  const int*   names_s = (const int*)d_in[0];
  const int*   ei_s    = (const int*)d_in[1];
  const float* ea_s    = (const float*)d_in[2];
  const int*   bat_s   = (const int*)d_in[3];
  const int*   names_g = (const int*)d_in[4];
  const int*   ei_g    = (const int*)d_in[5];
  const float* ea_g    = (const float*)d_in[6];
  const int*   bat_g   = (const int*)d_in[7];
  const float* depth   = (const float*)d_in[8];
  const float* idW1 = (const float*)d_in[9],  *idb1 = (const float*)d_in[10];
  const float* idW2 = (const float*)d_in[11], *idb2 = (const float*)d_in[12];
  const float* edW1 = (const float*)d_in[13], *edb1 = (const float*)d_in[14];
  const float* edW2 = (const float*)d_in[15], *edb2 = (const float*)d_in[16];
  const float* s1W1 = (const float*)d_in[17], *s1b1 = (const float*)d_in[18];
  const float* s1W2 = (const float*)d_in[19], *s1b2 = (const float*)d_in[20];
  const float* s2W1 = (const float*)d_in[21], *s2b1 = (const float*)d_in[22];
  const float* s2W2 = (const float*)d_in[23], *s2b2 = (const float*)d_in[24];
  const float* s2LW = (const float*)d_in[25], *s2Lb = (const float*)d_in[26];
  const float* g1W1 = (const float*)d_in[27], *g1b1 = (const float*)d_in[28];
  const float* g1W2 = (const float*)d_in[29], *g1b2 = (const float*)d_in[30];
  const float* g2W1 = (const float*)d_in[31], *g2b1 = (const float*)d_in[32];
  const float* g2W2 = (const float*)d_in[33], *g2b2 = (const float*)d_in[34];
  const float* g2LW = (const float*)d_in[35], *g2Lb = (const float*)d_in[36];
  const float* rW1  = (const float*)d_in[37], *rb1  = (const float*)d_in[38];
  const float* rW2  = (const float*)d_in[39], *rb2  = (const float*)d_in[40];
  (void)in_sizes; (void)n_in; (void)out_size; (void)ws_size;

  char* ws = (char*)d_ws;
  size_t off = 0;
  auto alloc = [&](size_t bytes) -> char* {
    char* p = ws + off;
    off += (bytes + 255) & ~(size_t)255;
    return p;
  };
  float* tabs    = (float*)alloc((size_t)TAB_TOTAL * 4);
  float* bufA    = (float*)alloc((size_t)NN * 64 * 4);       // per-graph x0 -> x1 -> x2
  float* bufB    = (float*)alloc((size_t)NN * 64 * 4);       // per-graph h1 -> h2
  int2*  colattr = (int2*) alloc((size_t)2 * NEDG * 8);      // both graphs
  int*   cnt     = (int*)  alloc((size_t)2 * NN * 4);
  int*   rowptr  = (int*)  alloc((size_t)(2 * NN + 1) * 4);
  int*   wp      = (int*)  alloc((size_t)2 * NN * 4);
  int*   bsum    = (int*)  alloc(1024 * 4);
  int*   bcnt    = (int*)  alloc((size_t)NBAT * 4);
  int*   brow    = (int*)  alloc((size_t)(NBAT + 1) * 4);
  float* pool_s  = (float*)alloc((size_t)NBAT * 64 * 4);
  float* pool_g  = (float*)alloc((size_t)NBAT * 64 * 4);

  const int NB2 = (2 * NN + 255) / 256;  // 782 blocks over both graphs' nodes

  build_tables<<<1, 256, 0, stream>>>(edW1, edb1, edW2, edb2, s2LW, s2Lb, g2LW, g2Lb, tabs);

  // --- merged CSR build for BOTH graphs
  hipMemsetAsync(cnt, 0, (size_t)2 * NN * 4, stream);
  hist_dst_dual<<<2 * EBLK, 256, 0, stream>>>(ei_s + NEDG, ei_g + NEDG, cnt);
  block_sums<<<NB2, 256, 0, stream>>>(cnt, bsum, 2 * NN);
  scan_partials<<<1, 1024, 0, stream>>>(bsum, NB2);
  write_rowptr<<<NB2, 256, 0, stream>>>(cnt, bsum, rowptr, wp, 2 * NN, 2 * NEDG);
  csr_fill_dual<<<2 * EBLK, 256, 0, stream>>>(ei_s, ei_s + NEDG, ea_s,
                                              ei_g, ei_g + NEDG, ea_g,
                                              tabs, wp, colattr);

  auto encoder = [&](const int* names, const int* bat, const int* rp,
                     const float* c1W1, const float* c1b1, const float* c1W2, const float* c1b2,
                     const float* c2W1, const float* c2b1, const float* c2W2, const float* c2b2,
                     int enc, float* pool) {
    node_embed<<<391, 256, 0, stream>>>(names, idW1, idb1, idW2, idb2, bufA);
    conv1_agg<<<NN / 4, 256, 0, stream>>>(bufA, rp, colattr, tabs, bufB);
    node_mlp16<32><<<NN / 16, 256, 0, stream>>>(bufB, c1W1, c1b1, c1W2, c1b2, bufA);
    conv2_agg<<<NN / 4, 256, 0, stream>>>(bufA, rp, colattr, tabs, enc, bufB);
    node_mlp16<64><<<NN / 16, 256, 0, stream>>>(bufB, c2W1, c2b1, c2W2, c2b2, bufA);
    hipMemsetAsync(bcnt, 0, (size_t)NBAT * 4, stream);
    hist_batch<<<391, 256, 0, stream>>>(bat, bcnt);
    batch_rowptr<<<1, 512, 0, stream>>>(bcnt, brow);
    pool_mean<<<NBAT, 256, 0, stream>>>(bufA, brow, pool);
  };

  encoder(names_s, bat_s, rowptr,      s1W1, s1b1, s1W2, s1b2, s2W1, s2b1, s2W2, s2b2, 0, pool_s);
  encoder(names_g, bat_g, rowptr + NN, g1W1, g1b1, g1W2, g1b2, g2W1, g2b1, g2W2, g2b2, 1, pool_g);

  regressor16<<<32, 256, 0, stream>>>(pool_s, pool_g, depth, rW1, rb1, rW2, rb2, (float*)d_out);
}

// Round 6
// 1111.050 us; speedup vs baseline: 1.3508x; 1.3508x over previous
//
#include <hip/hip_runtime.h>
#include <stdint.h>

namespace {

constexpr int NN   = 100000;    // nodes per graph
constexpr int NEDG = 1600000;   // edges per graph
constexpr int NBAT = 512;       // graphs per batch
constexpr int NSEG = 33;        // piecewise-linear segments of edge MLP (32 breakpoints)
constexpr int EBLK = NEDG / 256;  // 6250 blocks (one thread = one edge per graph)

// table layout (floats): bp[32] | d1[NSEG*32] | c1[NSEG*32] | per-enc {d2[NSEG*64], c2[NSEG*64]} x2
constexpr int TAB_BP = 0;
constexpr int TAB_D1 = 32;
constexpr int TAB_C1 = TAB_D1 + NSEG * 32;
constexpr int TAB_E2 = TAB_C1 + NSEG * 32;
constexpr int TAB_TOTAL = TAB_E2 + 4 * NSEG * 64;

__device__ __forceinline__ float relu_(float x) { return fmaxf(x, 0.0f); }

__device__ __forceinline__ float4 shfl_xor4(float4 v, int m) {
  return make_float4(__shfl_xor(v.x, m), __shfl_xor(v.y, m),
                     __shfl_xor(v.z, m), __shfl_xor(v.w, m));
}

// ---------------------------------------------------------------------------
// Precompute piecewise-linear tables for e(a) = relu(a*W1+b1)@W2+b2 and the
// folded e2(a) = e(a)@linW + linb. Exact reassociation of the reference math.
// ---------------------------------------------------------------------------
__global__ void build_tables(const float* __restrict__ eW1, const float* __restrict__ eb1,
                             const float* __restrict__ eW2, const float* __restrict__ eb2,
                             const float* __restrict__ sLW, const float* __restrict__ sLb,
                             const float* __restrict__ gLW, const float* __restrict__ gLb,
                             float* __restrict__ tabs) {
  __shared__ float traw[32];
  __shared__ float ts[32];
  __shared__ float dt[NSEG * 32];
  __shared__ float ct[NSEG * 32];
  int tid = threadIdx.x;
  if (tid < 32) {
    float w = eW1[tid], b = eb1[tid];
    traw[tid] = (w != 0.0f) ? (-b / w) : 3.0e38f;
  }
  __syncthreads();
  if (tid < 32) {  // rank sort (stable for duplicates)
    float v = traw[tid];
    int r = 0;
    for (int j = 0; j < 32; ++j) {
      float u = traw[j];
      r += (u < v) || (u == v && j < tid);
    }
    ts[r] = v;
  }
  __syncthreads();
  if (tid < 32) tabs[TAB_BP + tid] = ts[tid];
  for (int idx = tid; idx < NSEG * 32; idx += blockDim.x) {
    int s = idx >> 5, j = idx & 31;
    float a;  // representative point strictly inside segment s: (ts[s-1], ts[s]]
    if (s == 0)            a = ts[0] - 1.0f;
    else if (s == NSEG - 1) a = ts[31] + 1.0f;
    else                   a = 0.5f * ts[s - 1] + 0.5f * ts[s];
    float d = 0.0f, c = 0.0f;
    for (int i = 0; i < 32; ++i) {
      float w = eW1[i], b = eb1[i];
      if (fmaf(a, w, b) > 0.0f) {
        float w2 = eW2[i * 32 + j];
        d = fmaf(w, w2, d);
        c = fmaf(b, w2, c);
      }
    }
    c += eb2[j];
    dt[idx] = d; ct[idx] = c;
    tabs[TAB_D1 + idx] = d;
    tabs[TAB_C1 + idx] = c;
  }
  __syncthreads();
  for (int idx = tid; idx < NSEG * 64; idx += blockDim.x) {
    int s = idx >> 6, k = idx & 63;
    float ds = 0.f, cs = 0.f, dg = 0.f, cg = 0.f;
    for (int j = 0; j < 32; ++j) {
      float dv = dt[s * 32 + j], cv = ct[s * 32 + j];
      float ws = sLW[j * 64 + k], wg = gLW[j * 64 + k];
      ds = fmaf(dv, ws, ds); cs = fmaf(cv, ws, cs);
      dg = fmaf(dv, wg, dg); cg = fmaf(cv, wg, cg);
    }
    cs += sLb[k]; cg += gLb[k];
    tabs[TAB_E2 + idx]                 = ds;
    tabs[TAB_E2 + NSEG * 64 + idx]     = cs;
    tabs[TAB_E2 + 2 * NSEG * 64 + idx] = dg;
    tabs[TAB_E2 + 3 * NSEG * 64 + idx] = cg;
  }
}

// ---------------------------------------------------------------------------
// x0[n,32] = MLP2(clip((names+2)/SCALE,0,1))
// ---------------------------------------------------------------------------
__global__ __launch_bounds__(256, 2) void node_embed(
    const int* __restrict__ names,
    const float* __restrict__ W1, const float* __restrict__ b1,
    const float* __restrict__ W2, const float* __restrict__ b2,
    float* __restrict__ x0) {
  int n = blockIdx.x * 256 + threadIdx.x;
  if (n >= NN) return;
  float norm = ((float)names[n] + 2.0f) / 281474976710655.0f;
  norm = fminf(fmaxf(norm, 0.0f), 1.0f);
  float h[32];
#pragma unroll
  for (int i = 0; i < 32; ++i) h[i] = relu_(fmaf(norm, W1[i], b1[i]));
  float4* out = (float4*)(x0 + (size_t)n * 32);
  for (int j0 = 0; j0 < 32; j0 += 4) {
    float a0 = b2[j0], a1 = b2[j0 + 1], a2 = b2[j0 + 2], a3 = b2[j0 + 3];
#pragma unroll
    for (int i = 0; i < 32; ++i) {
      float hv = h[i];
      a0 = fmaf(hv, W2[i * 32 + j0],     a0);
      a1 = fmaf(hv, W2[i * 32 + j0 + 1], a1);
      a2 = fmaf(hv, W2[i * 32 + j0 + 2], a2);
      a3 = fmaf(hv, W2[i * 32 + j0 + 3], a3);
    }
    out[j0 >> 2] = make_float4(a0, a1, a2, a3);
  }
}

// ---------------------------------------------------------------------------
// Dual-graph CSR-by-dst build. Each thread handles edge e of graph s AND
// edge e of graph g: two fully independent atomic chains in flight per
// thread (disjoint counter regions: graph-g node bins offset by NN).
// ---------------------------------------------------------------------------
__global__ __launch_bounds__(256) void hist_dst_dual2(
    const int* __restrict__ dst_s, const int* __restrict__ dst_g,
    int* __restrict__ cnt) {
  int e = blockIdx.x * 256 + threadIdx.x;  // grid exact: EBLK
  int d0 = dst_s[e];
  int d1 = dst_g[e] + NN;
  atomicAdd(&cnt[d0], 1);
  atomicAdd(&cnt[d1], 1);
}

__global__ __launch_bounds__(256) void block_sums(const int* __restrict__ cnt, int* __restrict__ bsum, int n) {
  __shared__ int s[256];
  int i = blockIdx.x * 256 + threadIdx.x;
  s[threadIdx.x] = (i < n) ? cnt[i] : 0;
  __syncthreads();
  for (int st = 128; st > 0; st >>= 1) {
    if ((int)threadIdx.x < st) s[threadIdx.x] += s[threadIdx.x + st];
    __syncthreads();
  }
  if (threadIdx.x == 0) bsum[blockIdx.x] = s[0];
}

__global__ __launch_bounds__(1024) void scan_partials(int* __restrict__ bsum, int nb) {
  __shared__ int s[1024];
  int v = ((int)threadIdx.x < nb) ? bsum[threadIdx.x] : 0;
  s[threadIdx.x] = v;
  __syncthreads();
  for (int st = 1; st < 1024; st <<= 1) {
    int t = ((int)threadIdx.x >= st) ? s[threadIdx.x - st] : 0;
    __syncthreads();
    s[threadIdx.x] += t;
    __syncthreads();
  }
  if ((int)threadIdx.x < nb) bsum[threadIdx.x] = s[threadIdx.x] - v;  // exclusive
}

__global__ __launch_bounds__(256) void write_rowptr(
    const int* __restrict__ cnt, const int* __restrict__ bsum,
    int* __restrict__ rowptr, int* __restrict__ wp, int n, int total) {
  __shared__ int s[256];
  int i = blockIdx.x * 256 + threadIdx.x;
  int v = (i < n) ? cnt[i] : 0;
  s[threadIdx.x] = v;
  __syncthreads();
  for (int st = 1; st < 256; st <<= 1) {
    int t = ((int)threadIdx.x >= st) ? s[threadIdx.x - st] : 0;
    __syncthreads();
    s[threadIdx.x] += t;
    __syncthreads();
  }
  int excl = s[threadIdx.x] - v + bsum[blockIdx.x];
  if (i < n) { rowptr[i] = excl; wp[i] = excl; }
  if (i == n - 1) rowptr[n] = total;
}

// Two independent atomic+scatter chains per thread (s-edge + g-edge).
// Breakpoints in LDS; unrolled 32-compare for the segment id.
__global__ __launch_bounds__(256) void csr_fill_dual2(
    const int* __restrict__ src_s, const int* __restrict__ dst_s, const float* __restrict__ attr_s,
    const int* __restrict__ src_g, const int* __restrict__ dst_g, const float* __restrict__ attr_g,
    const float* __restrict__ tabs, int* __restrict__ wp, int2* __restrict__ colattr) {
  __shared__ float bp[32];
  if (threadIdx.x < 32) bp[threadIdx.x] = tabs[TAB_BP + threadIdx.x];
  __syncthreads();
  int e = blockIdx.x * 256 + threadIdx.x;  // grid exact: EBLK
  int sl0 = src_s[e], d0 = dst_s[e];
  float a0 = attr_s[e];
  int sl1 = src_g[e], d1 = dst_g[e] + NN;
  float a1 = attr_g[e];
  int g0 = 0, g1 = 0;  // seg = #(bp < a)
#pragma unroll
  for (int i = 0; i < 32; ++i) {
    float b = bp[i];
    g0 += (b < a0);
    g1 += (b < a1);
  }
  int p0 = atomicAdd(&wp[d0], 1);
  int p1 = atomicAdd(&wp[d1], 1);
  colattr[p0] = make_int2(sl0 | (g0 << 20), __float_as_int(a0));  // src<2^17, seg<64
  colattr[p1] = make_int2(sl1 | (g1 << 20), __float_as_int(a1));
}

// ---------------------------------------------------------------------------
// GINE aggregation, dst-major. One WAVE per node; wave processes several
// edges concurrently (sub = edge slot) so 16 row gathers are in flight per
// wave. hb[n] = x[n] + sum_j relu(x[src_j] + e_j). src ids are graph-local.
// ---------------------------------------------------------------------------
__global__ __launch_bounds__(256) void conv1_agg(
    const float* __restrict__ x0, const int* __restrict__ rowptr,
    const int2* __restrict__ colattr, const float* __restrict__ tabs,
    float* __restrict__ hb) {
  __shared__ float dt[NSEG * 32];
  __shared__ float ct[NSEG * 32];
  for (int i = threadIdx.x; i < NSEG * 32; i += 256) {
    dt[i] = tabs[TAB_D1 + i];
    ct[i] = tabs[TAB_C1 + i];
  }
  __syncthreads();
  int n = blockIdx.x * 4 + (threadIdx.x >> 6);  // grid exact: NN/4
  int lane = threadIdx.x & 63;
  int sub = lane & 7;        // 8 edges in flight (x2 unroll = 16)
  int f0  = (lane >> 3) * 4; // 8 float4 chunks -> 32 features
  int beg = rowptr[n], end = rowptr[n + 1];
  float4 acc = make_float4(0.f, 0.f, 0.f, 0.f);
  for (int k = beg + sub; k < end; k += 16) {
    int2 ca0 = colattr[k];
    int kb = k + 8;
    bool h1 = kb < end;
    int2 ca1 = h1 ? colattr[kb] : ca0;
    unsigned p0 = (unsigned)ca0.x, p1 = (unsigned)ca1.x;
    int s0 = (int)(p0 & 0xFFFFFu), g0 = (int)(p0 >> 20);
    int s1 = (int)(p1 & 0xFFFFFu), g1 = (int)(p1 >> 20);
    float a0 = __int_as_float(ca0.y), a1 = __int_as_float(ca1.y);
    float4 xv0 = *(const float4*)(x0 + (size_t)s0 * 32 + f0);
    float4 xv1 = *(const float4*)(x0 + (size_t)s1 * 32 + f0);
    float4 d0 = *(const float4*)&dt[g0 * 32 + f0];
    float4 c0 = *(const float4*)&ct[g0 * 32 + f0];
    float4 d1 = *(const float4*)&dt[g1 * 32 + f0];
    float4 c1 = *(const float4*)&ct[g1 * 32 + f0];
    acc.x += relu_(xv0.x + fmaf(a0, d0.x, c0.x));
    acc.y += relu_(xv0.y + fmaf(a0, d0.y, c0.y));
    acc.z += relu_(xv0.z + fmaf(a0, d0.z, c0.z));
    acc.w += relu_(xv0.w + fmaf(a0, d0.w, c0.w));
    if (h1) {
      acc.x += relu_(xv1.x + fmaf(a1, d1.x, c1.x));
      acc.y += relu_(xv1.y + fmaf(a1, d1.y, c1.y));
      acc.z += relu_(xv1.z + fmaf(a1, d1.z, c1.z));
      acc.w += relu_(xv1.w + fmaf(a1, d1.w, c1.w));
    }
  }
#pragma unroll
  for (int m = 1; m < 8; m <<= 1) {
    float4 o = shfl_xor4(acc, m);
    acc.x += o.x; acc.y += o.y; acc.z += o.z; acc.w += o.w;
  }
  if (sub == 0) {
    const float4 self = *(const float4*)(x0 + (size_t)n * 32 + f0);
    *(float4*)(hb + (size_t)n * 32 + f0) =
        make_float4(self.x + acc.x, self.y + acc.y, self.z + acc.z, self.w + acc.w);
  }
}

// conv2: sub=8 (8 edges in flight, x2 unroll = 16 gather pairs), each lane
// owns 8 features (two float4 loads per edge) -> 2x MLP vs the sub=4 layout.
__global__ __launch_bounds__(256) void conv2_agg(
    const float* __restrict__ x1, const int* __restrict__ rowptr,
    const int2* __restrict__ colattr, const float* __restrict__ tabs, int enc,
    float* __restrict__ hb) {
  __shared__ float dt[NSEG * 64];
  __shared__ float ct[NSEG * 64];
  const float* d2 = tabs + TAB_E2 + (size_t)enc * 2 * NSEG * 64;
  for (int i = threadIdx.x; i < NSEG * 64; i += 256) {
    dt[i] = d2[i];
    ct[i] = d2[NSEG * 64 + i];
  }
  __syncthreads();
  int n = blockIdx.x * 4 + (threadIdx.x >> 6);  // grid exact: NN/4
  int lane = threadIdx.x & 63;
  int sub = lane & 7;        // 8 edges in flight (x2 unroll = 16)
  int f0  = (lane >> 3) * 8; // 8 features per lane -> 64 features
  int beg = rowptr[n], end = rowptr[n + 1];
  float4 accA = make_float4(0.f, 0.f, 0.f, 0.f);
  float4 accB = make_float4(0.f, 0.f, 0.f, 0.f);
  for (int k = beg + sub; k < end; k += 16) {
    int2 ca0 = colattr[k];
    int kb = k + 8;
    bool h1 = kb < end;
    int2 ca1 = h1 ? colattr[kb] : ca0;
    unsigned p0 = (unsigned)ca0.x, p1 = (unsigned)ca1.x;
    int s0 = (int)(p0 & 0xFFFFFu), g0 = (int)(p0 >> 20);
    int s1 = (int)(p1 & 0xFFFFFu), g1 = (int)(p1 >> 20);
    float a0 = __int_as_float(ca0.y), a1 = __int_as_float(ca1.y);
    const float* r0 = x1 + (size_t)s0 * 64 + f0;
    const float* r1 = x1 + (size_t)s1 * 64 + f0;
    float4 xa0 = *(const float4*)r0;
    float4 xb0 = *(const float4*)(r0 + 4);
    float4 xa1 = *(const float4*)r1;
    float4 xb1 = *(const float4*)(r1 + 4);
    float4 da0 = *(const float4*)&dt[g0 * 64 + f0];
    float4 db0 = *(const float4*)&dt[g0 * 64 + f0 + 4];
    float4 ea0 = *(const float4*)&ct[g0 * 64 + f0];
    float4 eb0 = *(const float4*)&ct[g0 * 64 + f0 + 4];
    accA.x += relu_(xa0.x + fmaf(a0, da0.x, ea0.x));
    accA.y += relu_(xa0.y + fmaf(a0, da0.y, ea0.y));
    accA.z += relu_(xa0.z + fmaf(a0, da0.z, ea0.z));
    accA.w += relu_(xa0.w + fmaf(a0, da0.w, ea0.w));
    accB.x += relu_(xb0.x + fmaf(a0, db0.x, eb0.x));
    accB.y += relu_(xb0.y + fmaf(a0, db0.y, eb0.y));
    accB.z += relu_(xb0.z + fmaf(a0, db0.z, eb0.z));
    accB.w += relu_(xb0.w + fmaf(a0, db0.w, eb0.w));
    if (h1) {
      float4 da1 = *(const float4*)&dt[g1 * 64 + f0];
      float4 db1 = *(const float4*)&dt[g1 * 64 + f0 + 4];
      float4 ea1 = *(const float4*)&ct[g1 * 64 + f0];
      float4 eb1 = *(const float4*)&ct[g1 * 64 + f0 + 4];
      accA.x += relu_(xa1.x + fmaf(a1, da1.x, ea1.x));
      accA.y += relu_(xa1.y + fmaf(a1, da1.y, ea1.y));
      accA.z += relu_(xa1.z + fmaf(a1, da1.z, ea1.z));
      accA.w += relu_(xa1.w + fmaf(a1, da1.w, ea1.w));
      accB.x += relu_(xb1.x + fmaf(a1, db1.x, eb1.x));
      accB.y += relu_(xb1.y + fmaf(a1, db1.y, eb1.y));
      accB.z += relu_(xb1.z + fmaf(a1, db1.z, eb1.z));
      accB.w += relu_(xb1.w + fmaf(a1, db1.w, eb1.w));
    }
  }
#pragma unroll
  for (int m = 1; m < 8; m <<= 1) {
    float4 oA = shfl_xor4(accA, m);
    float4 oB = shfl_xor4(accB, m);
    accA.x += oA.x; accA.y += oA.y; accA.z += oA.z; accA.w += oA.w;
    accB.x += oB.x; accB.y += oB.y; accB.z += oB.z; accB.w += oB.w;
  }
  if (sub == 0) {
    const float* sp = x1 + (size_t)n * 64 + f0;
    const float4 sA = *(const float4*)sp;
    const float4 sB = *(const float4*)(sp + 4);
    float* op = hb + (size_t)n * 64 + f0;
    *(float4*)op       = make_float4(sA.x + accA.x, sA.y + accA.y, sA.z + accA.z, sA.w + accA.w);
    *(float4*)(op + 4) = make_float4(sB.x + accB.x, sB.y + accB.y, sB.z + accB.z, sB.w + accB.w);
  }
}

// ---------------------------------------------------------------------------
// Per-node MLP2 (IN -> 64 -> 64), relu on both layers + output (conv wrapper).
// Register-tiled VALU GEMM: 64 nodes/block, thread owns 4 nodes x 4 features
// (16 accumulators, ~48 VGPR -- no 64-element array, no spill). Per k: one
// ds_read_b128 (transposed activations) + one L1 b128 (weights) -> 16 FMAs.
// ---------------------------------------------------------------------------
template <int IN>
__global__ __launch_bounds__(256) void node_mlp_tile(
    const float* __restrict__ hin,
    const float* __restrict__ W1, const float* __restrict__ b1,
    const float* __restrict__ W2, const float* __restrict__ b2,
    float* __restrict__ xout) {
  __shared__ float hsT[IN][65];   // [k][node], stride 65 -> conflict-free
  __shared__ float ysT[64][65];   // [feature][node]
  int base = blockIdx.x * 64;
  int count = NN - base; if (count > 64) count = 64;
  for (int idx = threadIdx.x; idx < 64 * IN; idx += 256) {
    int node = idx / IN, k = idx - node * IN;
    float v = (node < count) ? hin[(size_t)(base + node) * IN + k] : 0.0f;
    hsT[k][node] = v;
  }
  __syncthreads();
  int nt = threadIdx.x >> 4;   // node quad [0,16)
  int jx = threadIdx.x & 15;   // feature quad [0,16)
  int n0 = nt * 4, f0 = jx * 4;
  float4 acc0, acc1, acc2, acc3;
  {
    const float4 b = *(const float4*)(b1 + f0);
    acc0 = b; acc1 = b; acc2 = b; acc3 = b;
  }
  for (int k = 0; k < IN; ++k) {
    const float4 h = *(const float4*)&hsT[k][n0];
    const float4 w = *(const float4*)(W1 + k * 64 + f0);
    acc0.x = fmaf(h.x, w.x, acc0.x); acc0.y = fmaf(h.x, w.y, acc0.y);
    acc0.z = fmaf(h.x, w.z, acc0.z); acc0.w = fmaf(h.x, w.w, acc0.w);
    acc1.x = fmaf(h.y, w.x, acc1.x); acc1.y = fmaf(h.y, w.y, acc1.y);
    acc1.z = fmaf(h.y, w.z, acc1.z); acc1.w = fmaf(h.y, w.w, acc1.w);
    acc2.x = fmaf(h.z, w.x, acc2.x); acc2.y = fmaf(h.z, w.y, acc2.y);
    acc2.z = fmaf(h.z, w.z, acc2.z); acc2.w = fmaf(h.z, w.w, acc2.w);
    acc3.x = fmaf(h.w, w.x, acc3.x); acc3.y = fmaf(h.w, w.y, acc3.y);
    acc3.z = fmaf(h.w, w.z, acc3.z); acc3.w = fmaf(h.w, w.w, acc3.w);
  }
  ysT[f0 + 0][n0 + 0] = relu_(acc0.x); ysT[f0 + 1][n0 + 0] = relu_(acc0.y);
  ysT[f0 + 2][n0 + 0] = relu_(acc0.z); ysT[f0 + 3][n0 + 0] = relu_(acc0.w);
  ysT[f0 + 0][n0 + 1] = relu_(acc1.x); ysT[f0 + 1][n0 + 1] = relu_(acc1.y);
  ysT[f0 + 2][n0 + 1] = relu_(acc1.z); ysT[f0 + 3][n0 + 1] = relu_(acc1.w);
  ysT[f0 + 0][n0 + 2] = relu_(acc2.x); ysT[f0 + 1][n0 + 2] = relu_(acc2.y);
  ysT[f0 + 2][n0 + 2] = relu_(acc2.z); ysT[f0 + 3][n0 + 2] = relu_(acc2.w);
  ysT[f0 + 0][n0 + 3] = relu_(acc3.x); ysT[f0 + 1][n0 + 3] = relu_(acc3.y);
  ysT[f0 + 2][n0 + 3] = relu_(acc3.z); ysT[f0 + 3][n0 + 3] = relu_(acc3.w);
  __syncthreads();
  {
    const float4 b = *(const float4*)(b2 + f0);
    acc0 = b; acc1 = b; acc2 = b; acc3 = b;
  }
  for (int k = 0; k < 64; ++k) {
    const float4 h = *(const float4*)&ysT[k][n0];
    const float4 w = *(const float4*)(W2 + k * 64 + f0);
    acc0.x = fmaf(h.x, w.x, acc0.x); acc0.y = fmaf(h.x, w.y, acc0.y);
    acc0.z = fmaf(h.x, w.z, acc0.z); acc0.w = fmaf(h.x, w.w, acc0.w);
    acc1.x = fmaf(h.y, w.x, acc1.x); acc1.y = fmaf(h.y, w.y, acc1.y);
    acc1.z = fmaf(h.y, w.z, acc1.z); acc1.w = fmaf(h.y, w.w, acc1.w);
    acc2.x = fmaf(h.z, w.x, acc2.x); acc2.y = fmaf(h.z, w.y, acc2.y);
    acc2.z = fmaf(h.z, w.z, acc2.z); acc2.w = fmaf(h.z, w.w, acc2.w);
    acc3.x = fmaf(h.w, w.x, acc3.x); acc3.y = fmaf(h.w, w.y, acc3.y);
    acc3.z = fmaf(h.w, w.z, acc3.z); acc3.w = fmaf(h.w, w.w, acc3.w);
  }
  float4 o;
  if (0 < count - n0) {
    o = make_float4(relu_(acc0.x), relu_(acc0.y), relu_(acc0.z), relu_(acc0.w));
    *(float4*)(xout + (size_t)(base + n0 + 0) * 64 + f0) = o;
  }
  if (1 < count - n0) {
    o = make_float4(relu_(acc1.x), relu_(acc1.y), relu_(acc1.z), relu_(acc1.w));
    *(float4*)(xout + (size_t)(base + n0 + 1) * 64 + f0) = o;
  }
  if (2 < count - n0) {
    o = make_float4(relu_(acc2.x), relu_(acc2.y), relu_(acc2.z), relu_(acc2.w));
    *(float4*)(xout + (size_t)(base + n0 + 2) * 64 + f0) = o;
  }
  if (3 < count - n0) {
    o = make_float4(relu_(acc3.x), relu_(acc3.y), relu_(acc3.z), relu_(acc3.w));
    *(float4*)(xout + (size_t)(base + n0 + 3) * 64 + f0) = o;
  }
}

// ---------------------------------------------------------------------------
// Batch boundaries from the SORTED batch array (no atomics): start[b] =
// first i with bat[i] >= b; start[NBAT] = NN. Handles empty batches.
// ---------------------------------------------------------------------------
__global__ __launch_bounds__(256) void batch_bounds_dual(
    const int* __restrict__ bat_s, const int* __restrict__ bat_g,
    int* __restrict__ start_s, int* __restrict__ start_g) {
  int half = blockIdx.x >= 391;
  const int* bat = half ? bat_g : bat_s;
  int* start = half ? start_g : start_s;
  int i = (blockIdx.x - half * 391) * 256 + threadIdx.x;
  if (i >= NN) return;
  int cur = bat[i];
  int prev = (i == 0) ? -1 : bat[i - 1];
  for (int b = prev + 1; b <= cur; ++b) start[b] = i;
  if (i == NN - 1) {
    for (int b = cur + 1; b <= NBAT; ++b) start[b] = NN;
  }
}

__global__ __launch_bounds__(256) void pool_mean(
    const float* __restrict__ x2, const int* __restrict__ start, float* __restrict__ pool) {
  __shared__ float s[4][64];
  int g = blockIdx.x;
  int f = threadIdx.x & 63, c = threadIdx.x >> 6;
  int beg = start[g], end = start[g + 1];
  float acc = 0.0f;
  for (int n = beg + c; n < end; n += 4) acc += x2[(size_t)n * 64 + f];
  s[c][f] = acc;
  __syncthreads();
  if (c == 0) {
    float tot = s[0][f] + s[1][f] + s[2][f] + s[3][f];
    float m = (float)(end - beg);
    pool[g * 64 + f] = tot / fmaxf(m, 1.0f);
  }
}

// ---------------------------------------------------------------------------
// regressor: out[b] = relu([s|g|depth] @ rW1 + rb1) @ rW2 + rb2
// 16 lanes per row (no register arrays).
// ---------------------------------------------------------------------------
__global__ __launch_bounds__(256) void regressor16(
    const float* __restrict__ ps, const float* __restrict__ pg, const float* __restrict__ depth,
    const float* __restrict__ W1, const float* __restrict__ b1,
    const float* __restrict__ W2, const float* __restrict__ b2,
    float* __restrict__ out) {
  __shared__ float zs[16][132];   // [row][k], k in [0,129)
  __shared__ float ys[64][17];
  int base = blockIdx.x * 16;     // grid 32 blocks x 16 rows = 512 exact
  for (int i = threadIdx.x; i < 16 * 64; i += 256) {
    int ln = i >> 6, k = i & 63;
    zs[ln][k]      = ps[(size_t)(base + ln) * 64 + k];
    zs[ln][64 + k] = pg[(size_t)(base + ln) * 64 + k];
  }
  if (threadIdx.x < 16) zs[threadIdx.x][128] = depth[base + threadIdx.x];
  __syncthreads();
  int g = threadIdx.x >> 4;
  int j = threadIdx.x & 15;
  int f0 = j * 4;
  float a0, a1, a2, a3;
  {
    const float4 b = *(const float4*)(b1 + f0);
    a0 = b.x; a1 = b.y; a2 = b.z; a3 = b.w;
  }
  for (int k = 0; k < 129; ++k) {
    float zv = zs[g][k];
    const float4 w = *(const float4*)(W1 + k * 64 + f0);
    a0 = fmaf(zv, w.x, a0); a1 = fmaf(zv, w.y, a1);
    a2 = fmaf(zv, w.z, a2); a3 = fmaf(zv, w.w, a3);
  }
  ys[f0 + 0][g] = relu_(a0);
  ys[f0 + 1][g] = relu_(a1);
  ys[f0 + 2][g] = relu_(a2);
  ys[f0 + 3][g] = relu_(a3);
  __syncthreads();
  float s = ys[f0 + 0][g] * W2[f0 + 0] + ys[f0 + 1][g] * W2[f0 + 1] +
            ys[f0 + 2][g] * W2[f0 + 2] + ys[f0 + 3][g] * W2[f0 + 3];
#pragma unroll
  for (int m = 1; m < 16; m <<= 1) s += __shfl_xor(s, m);
  if (j == 0) out[base + g] = s + b2[0];
}

}  // namespace

extern "C" void kernel_launch(void* const* d_in, const int* in_sizes, int n_in,
                              void* d_out, int out_size, void* d_ws, size_t ws_size,
                              hipStream_t stream) {
  const int*   names_s = (const int*)d_in[0];
  const int*   ei_s    = (const int*)d_in[1];
  const float* ea_s    = (const float*)d_in[2];
  const int*   bat_s   = (const int*)d_in[3];
  const int*   names_g = (const int*)d_in[4];
  const int*   ei_g    = (const int*)d_in[5];
  const float* ea_g    = (const float*)d_in[6];
  const int*   bat_g   = (const int*)d_in[7];
  const float* depth   = (const float*)d_in[8];
  const float* idW1 = (const float*)d_in[9],  *idb1 = (const float*)d_in[10];
  const float* idW2 = (const float*)d_in[11], *idb2 = (const float*)d_in[12];
  const float* edW1 = (const float*)d_in[13], *edb1 = (const float*)d_in[14];
  const float* edW2 = (const float*)d_in[15], *edb2 = (const float*)d_in[16];
  const float* s1W1 = (const float*)d_in[17], *s1b1 = (const float*)d_in[18];
  const float* s1W2 = (const float*)d_in[19], *s1b2 = (const float*)d_in[20];
  const float* s2W1 = (const float*)d_in[21], *s2b1 = (const float*)d_in[22];
  const float* s2W2 = (const float*)d_in[23], *s2b2 = (const float*)d_in[24];
  const float* s2LW = (const float*)d_in[25], *s2Lb = (const float*)d_in[26];
  const float* g1W1 = (const float*)d_in[27], *g1b1 = (const float*)d_in[28];
  const float* g1W2 = (const float*)d_in[29], *g1b2 = (const float*)d_in[30];
  const float* g2W1 = (const float*)d_in[31], *g2b1 = (const float*)d_in[32];
  const float* g2W2 = (const float*)d_in[33], *g2b2 = (const float*)d_in[34];
  const float* g2LW = (const float*)d_in[35], *g2Lb = (const float*)d_in[36];
  const float* rW1  = (const float*)d_in[37], *rb1  = (const float*)d_in[38];
  const float* rW2  = (const float*)d_in[39], *rb2  = (const float*)d_in[40];
  (void)in_sizes; (void)n_in; (void)out_size; (void)ws_size;

  char* ws = (char*)d_ws;
  size_t off = 0;
  auto alloc = [&](size_t bytes) -> char* {
    char* p = ws + off;
    off += (bytes + 255) & ~(size_t)255;
    return p;
  };
  float* tabs    = (float*)alloc((size_t)TAB_TOTAL * 4);
  float* bufA    = (float*)alloc((size_t)NN * 64 * 4);       // per-graph x0 -> x1 -> x2
  float* bufB    = (float*)alloc((size_t)NN * 64 * 4);       // per-graph h1 -> h2
  int2*  colattr = (int2*) alloc((size_t)2 * NEDG * 8);      // both graphs
  int*   cnt     = (int*)  alloc((size_t)2 * NN * 4);
  int*   rowptr  = (int*)  alloc((size_t)(2 * NN + 1) * 4);
  int*   wp      = (int*)  alloc((size_t)2 * NN * 4);
  int*   bsum    = (int*)  alloc(1024 * 4);
  int*   start_s = (int*)  alloc((size_t)(NBAT + 1) * 4);
  int*   start_g = (int*)  alloc((size_t)(NBAT + 1) * 4);
  float* pool_s  = (float*)alloc((size_t)NBAT * 64 * 4);
  float* pool_g  = (float*)alloc((size_t)NBAT * 64 * 4);

  const int NB2 = (2 * NN + 255) / 256;  // 782 blocks over both graphs' nodes

  build_tables<<<1, 256, 0, stream>>>(edW1, edb1, edW2, edb2, s2LW, s2Lb, g2LW, g2Lb, tabs);

  // --- merged CSR build for BOTH graphs, 2 independent atomic chains/thread
  hipMemsetAsync(cnt, 0, (size_t)2 * NN * 4, stream);
  hist_dst_dual2<<<EBLK, 256, 0, stream>>>(ei_s + NEDG, ei_g + NEDG, cnt);
  block_sums<<<NB2, 256, 0, stream>>>(cnt, bsum, 2 * NN);
  scan_partials<<<1, 1024, 0, stream>>>(bsum, NB2);
  write_rowptr<<<NB2, 256, 0, stream>>>(cnt, bsum, rowptr, wp, 2 * NN, 2 * NEDG);
  csr_fill_dual2<<<EBLK, 256, 0, stream>>>(ei_s, ei_s + NEDG, ea_s,
                                           ei_g, ei_g + NEDG, ea_g,
                                           tabs, wp, colattr);
  batch_bounds_dual<<<782, 256, 0, stream>>>(bat_s, bat_g, start_s, start_g);

  auto encoder = [&](const int* names, const int* start, const int* rp,
                     const float* c1W1, const float* c1b1, const float* c1W2, const float* c1b2,
                     const float* c2W1, const float* c2b1, const float* c2W2, const float* c2b2,
                     int enc, float* pool) {
    node_embed<<<391, 256, 0, stream>>>(names, idW1, idb1, idW2, idb2, bufA);
    conv1_agg<<<NN / 4, 256, 0, stream>>>(bufA, rp, colattr, tabs, bufB);
    node_mlp_tile<32><<<(NN + 63) / 64, 256, 0, stream>>>(bufB, c1W1, c1b1, c1W2, c1b2, bufA);
    conv2_agg<<<NN / 4, 256, 0, stream>>>(bufA, rp, colattr, tabs, enc, bufB);
    node_mlp_tile<64><<<(NN + 63) / 64, 256, 0, stream>>>(bufB, c2W1, c2b1, c2W2, c2b2, bufA);
    pool_mean<<<NBAT, 256, 0, stream>>>(bufA, start, pool);
  };

  encoder(names_s, start_s, rowptr,      s1W1, s1b1, s1W2, s1b2, s2W1, s2b1, s2W2, s2b2, 0, pool_s);
  encoder(names_g, start_g, rowptr + NN, g1W1, g1b1, g1W2, g1b2, g2W1, g2b1, g2W2, g2b2, 1, pool_g);

  regressor16<<<32, 256, 0, stream>>>(pool_s, pool_g, depth, rW1, rb1, rW2, rb2, (float*)d_out);
}

// Round 7
// 955.223 us; speedup vs baseline: 1.5712x; 1.1631x over previous
//
#include <hip/hip_runtime.h>
#include <stdint.h>

namespace {

constexpr int NN   = 100000;    // nodes per graph
constexpr int NEDG = 1600000;   // edges per graph
constexpr int NBAT = 512;       // graphs per batch
constexpr int NSEG = 33;        // piecewise-linear segments of edge MLP (32 breakpoints)
constexpr int EBLK = NEDG / 256;  // 6250 blocks (one thread = one s-edge + one g-edge)

// bucket CSR build: 64 dst-nodes per bucket, 8 XCD-local sub-buckets
constexpr int NBUK   = 2 * NN / 64;  // 3125 buckets over both graphs' node space
constexpr int SUBCAP = 256;          // entries per sub-bucket (mean 128, ~11 sigma margin)
constexpr int BCAP   = 2048;         // 8 * SUBCAP

// table layout (floats): bp[32] | d1[NSEG*32] | c1[NSEG*32] | per-enc {d2[NSEG*64], c2[NSEG*64]} x2
constexpr int TAB_BP = 0;
constexpr int TAB_D1 = 32;
constexpr int TAB_C1 = TAB_D1 + NSEG * 32;
constexpr int TAB_E2 = TAB_C1 + NSEG * 32;
constexpr int TAB_TOTAL = TAB_E2 + 4 * NSEG * 64;

__device__ __forceinline__ float relu_(float x) { return fmaxf(x, 0.0f); }

__device__ __forceinline__ float4 shfl_xor4(float4 v, int m) {
  return make_float4(__shfl_xor(v.x, m), __shfl_xor(v.y, m),
                     __shfl_xor(v.z, m), __shfl_xor(v.w, m));
}

// ---------------------------------------------------------------------------
// Precompute piecewise-linear tables for e(a) = relu(a*W1+b1)@W2+b2 and the
// folded e2(a) = e(a)@linW + linb. Exact reassociation of the reference math.
// ---------------------------------------------------------------------------
__global__ void build_tables(const float* __restrict__ eW1, const float* __restrict__ eb1,
                             const float* __restrict__ eW2, const float* __restrict__ eb2,
                             const float* __restrict__ sLW, const float* __restrict__ sLb,
                             const float* __restrict__ gLW, const float* __restrict__ gLb,
                             float* __restrict__ tabs) {
  __shared__ float traw[32];
  __shared__ float ts[32];
  __shared__ float dt[NSEG * 32];
  __shared__ float ct[NSEG * 32];
  int tid = threadIdx.x;
  if (tid < 32) {
    float w = eW1[tid], b = eb1[tid];
    traw[tid] = (w != 0.0f) ? (-b / w) : 3.0e38f;
  }
  __syncthreads();
  if (tid < 32) {  // rank sort (stable for duplicates)
    float v = traw[tid];
    int r = 0;
    for (int j = 0; j < 32; ++j) {
      float u = traw[j];
      r += (u < v) || (u == v && j < tid);
    }
    ts[r] = v;
  }
  __syncthreads();
  if (tid < 32) tabs[TAB_BP + tid] = ts[tid];
  for (int idx = tid; idx < NSEG * 32; idx += blockDim.x) {
    int s = idx >> 5, j = idx & 31;
    float a;  // representative point strictly inside segment s: (ts[s-1], ts[s]]
    if (s == 0)            a = ts[0] - 1.0f;
    else if (s == NSEG - 1) a = ts[31] + 1.0f;
    else                   a = 0.5f * ts[s - 1] + 0.5f * ts[s];
    float d = 0.0f, c = 0.0f;
    for (int i = 0; i < 32; ++i) {
      float w = eW1[i], b = eb1[i];
      if (fmaf(a, w, b) > 0.0f) {
        float w2 = eW2[i * 32 + j];
        d = fmaf(w, w2, d);
        c = fmaf(b, w2, c);
      }
    }
    c += eb2[j];
    dt[idx] = d; ct[idx] = c;
    tabs[TAB_D1 + idx] = d;
    tabs[TAB_C1 + idx] = c;
  }
  __syncthreads();
  for (int idx = tid; idx < NSEG * 64; idx += blockDim.x) {
    int s = idx >> 6, k = idx & 63;
    float ds = 0.f, cs = 0.f, dg = 0.f, cg = 0.f;
    for (int j = 0; j < 32; ++j) {
      float dv = dt[s * 32 + j], cv = ct[s * 32 + j];
      float ws = sLW[j * 64 + k], wg = gLW[j * 64 + k];
      ds = fmaf(dv, ws, ds); cs = fmaf(cv, ws, cs);
      dg = fmaf(dv, wg, dg); cg = fmaf(cv, wg, cg);
    }
    cs += sLb[k]; cg += gLb[k];
    tabs[TAB_E2 + idx]                 = ds;
    tabs[TAB_E2 + NSEG * 64 + idx]     = cs;
    tabs[TAB_E2 + 2 * NSEG * 64 + idx] = dg;
    tabs[TAB_E2 + 3 * NSEG * 64 + idx] = cg;
  }
}

// ---------------------------------------------------------------------------
// x0[n,32] = MLP2(clip((names+2)/SCALE,0,1))
// ---------------------------------------------------------------------------
__global__ __launch_bounds__(256, 2) void node_embed(
    const int* __restrict__ names,
    const float* __restrict__ W1, const float* __restrict__ b1,
    const float* __restrict__ W2, const float* __restrict__ b2,
    float* __restrict__ x0) {
  int n = blockIdx.x * 256 + threadIdx.x;
  if (n >= NN) return;
  float norm = ((float)names[n] + 2.0f) / 281474976710655.0f;
  norm = fminf(fmaxf(norm, 0.0f), 1.0f);
  float h[32];
#pragma unroll
  for (int i = 0; i < 32; ++i) h[i] = relu_(fmaf(norm, W1[i], b1[i]));
  float4* out = (float4*)(x0 + (size_t)n * 32);
  for (int j0 = 0; j0 < 32; j0 += 4) {
    float a0 = b2[j0], a1 = b2[j0 + 1], a2 = b2[j0 + 2], a3 = b2[j0 + 3];
#pragma unroll
    for (int i = 0; i < 32; ++i) {
      float hv = h[i];
      a0 = fmaf(hv, W2[i * 32 + j0],     a0);
      a1 = fmaf(hv, W2[i * 32 + j0 + 1], a1);
      a2 = fmaf(hv, W2[i * 32 + j0 + 2], a2);
      a3 = fmaf(hv, W2[i * 32 + j0 + 3], a3);
    }
    out[j0 >> 2] = make_float4(a0, a1, a2, a3);
  }
}

// ---------------------------------------------------------------------------
// Bucketed CSR build. Round-6 showed the direct atomic+scatter fill is bound
// by ~8x L2 writeback amplification (198 MB for a 25.6 MB buffer): random 8B
// scatter means each 64B line is dirtied by ~8 threads on different XCDs.
// Pass 1 appends edges to 64-node buckets with 8 XCD-local sub-buckets
// (sub = blockIdx&7 tracks the XCD round-robin), so each line is filled by
// one XCD and the hot write set (~25K head lines) stays L2-resident.
// Entry: {src | dstLocal<<17, attr_bits}; seg is recomputed in pass 3.
// ---------------------------------------------------------------------------
__global__ __launch_bounds__(256) void bucket_scatter(
    const int* __restrict__ src_s, const int* __restrict__ dst_s, const float* __restrict__ attr_s,
    const int* __restrict__ src_g, const int* __restrict__ dst_g, const float* __restrict__ attr_g,
    int* __restrict__ bcnt, int2* __restrict__ bucket_mem) {
  int e = blockIdx.x * 256 + threadIdx.x;  // grid exact: EBLK
  int sub = blockIdx.x & 7;
  int d0 = dst_s[e], s0 = src_s[e];
  float a0 = attr_s[e];
  int d1 = dst_g[e] + NN, s1 = src_g[e];
  float a1 = attr_g[e];
  int b0 = d0 >> 6, b1 = d1 >> 6;
  int p0 = atomicAdd(&bcnt[b0 * 8 + sub], 1);
  int p1 = atomicAdd(&bcnt[b1 * 8 + sub], 1);
  if (p0 < SUBCAP)
    bucket_mem[(size_t)(b0 * 8 + sub) * SUBCAP + p0] =
        make_int2(s0 | ((d0 & 63) << 17), __float_as_int(a0));
  if (p1 < SUBCAP)
    bucket_mem[(size_t)(b1 * 8 + sub) * SUBCAP + p1] =
        make_int2(s1 | ((d1 & 63) << 17), __float_as_int(a1));
}

// One-block exclusive scan over the 3125 bucket totals (replaces the 200K-
// node histogram + 3-kernel scan chain of previous rounds entirely).
__global__ __launch_bounds__(1024) void bucket_scan(
    const int* __restrict__ bcnt, int* __restrict__ bbase, int* __restrict__ rowptr) {
  __shared__ int s[1024];
  int t = threadIdx.x;
  int loc[4];
  int sum = 0;
#pragma unroll
  for (int j = 0; j < 4; ++j) {
    int b = t * 4 + j;
    int v = 0;
    if (b < NBUK) {
#pragma unroll
      for (int x = 0; x < 8; ++x) v += min(bcnt[b * 8 + x], SUBCAP);
    }
    loc[j] = sum;
    sum += v;
  }
  s[t] = sum;
  __syncthreads();
  for (int st = 1; st < 1024; st <<= 1) {
    int v = (t >= st) ? s[t - st] : 0;
    __syncthreads();
    s[t] += v;
    __syncthreads();
  }
  int gexcl = s[t] - sum;
#pragma unroll
  for (int j = 0; j < 4; ++j) {
    int b = t * 4 + j;
    if (b < NBUK) bbase[b] = gexcl + loc[j];
  }
  if (t == 1023) rowptr[2 * NN] = s[1023];
}

// One block per bucket: entries -> LDS, 64-slot LDS histogram + scan gives
// per-node rowptr (plain stores, zero global atomics) and exact CSR slots;
// colattr writes land in the bucket's CONTIGUOUS range -> dense lines.
__global__ __launch_bounds__(256) void bucket_to_csr(
    const int* __restrict__ bcnt, const int* __restrict__ bbase,
    const int2* __restrict__ bucket_mem, const float* __restrict__ tabs,
    int* __restrict__ rowptr, int2* __restrict__ colattr) {
  __shared__ int2 ent[BCAP];       // 16 KB
  __shared__ int scnt[8], subof[9];
  __shared__ int excl[64];
  __shared__ int cursor[64];
  __shared__ float bp[32];
  int tid = threadIdx.x, b = blockIdx.x;  // grid exact: NBUK
  if (tid < 32) bp[tid] = tabs[TAB_BP + tid];
  if (tid < 8) scnt[tid] = min(bcnt[b * 8 + tid], SUBCAP);
  if (tid < 64) cursor[tid] = 0;  // histogram first
  __syncthreads();
  if (tid == 0) {
    int r = 0;
    for (int x = 0; x < 8; ++x) { subof[x] = r; r += scnt[x]; }
    subof[8] = r;
  }
  __syncthreads();
  for (int x = 0; x < 8; ++x) {
    int c = scnt[x], bo = subof[x];
    const int2* sp = bucket_mem + (size_t)(b * 8 + x) * SUBCAP;
    for (int i = tid; i < c; i += 256) ent[bo + i] = sp[i];
  }
  __syncthreads();
  int tot = subof[8];
  for (int i = tid; i < tot; i += 256)
    atomicAdd(&cursor[(ent[i].x >> 17) & 63], 1);
  __syncthreads();
  if (tid == 0) {
    int r = 0;
    for (int k = 0; k < 64; ++k) { int h = cursor[k]; excl[k] = r; r += h; }
  }
  __syncthreads();
  int gbase = bbase[b];
  if (tid < 64) {
    rowptr[b * 64 + tid] = gbase + excl[tid];  // NBUK*64 == 2*NN exactly
    cursor[tid] = excl[tid];
  }
  __syncthreads();
  for (int i = tid; i < tot; i += 256) {
    int2 e = ent[i];
    int dl = (e.x >> 17) & 63;
    int srcn = e.x & 0x1FFFF;
    float a = __int_as_float(e.y);
    int seg = 0;
#pragma unroll
    for (int k = 0; k < 32; ++k) seg += (bp[k] < a);
    int pos = gbase + atomicAdd(&cursor[dl], 1);
    colattr[pos] = make_int2(srcn | (seg << 20), e.y);  // src<2^17, seg<64
  }
}

// ---------------------------------------------------------------------------
// GINE aggregation, dst-major. One WAVE per node; wave processes several
// edges concurrently (sub = edge slot) so 16 row gathers are in flight per
// wave. hb[n] = x[n] + sum_j relu(x[src_j] + e_j). src ids are graph-local.
// ---------------------------------------------------------------------------
__global__ __launch_bounds__(256) void conv1_agg(
    const float* __restrict__ x0, const int* __restrict__ rowptr,
    const int2* __restrict__ colattr, const float* __restrict__ tabs,
    float* __restrict__ hb) {
  __shared__ float dt[NSEG * 32];
  __shared__ float ct[NSEG * 32];
  for (int i = threadIdx.x; i < NSEG * 32; i += 256) {
    dt[i] = tabs[TAB_D1 + i];
    ct[i] = tabs[TAB_C1 + i];
  }
  __syncthreads();
  int n = blockIdx.x * 4 + (threadIdx.x >> 6);  // grid exact: NN/4
  int lane = threadIdx.x & 63;
  int sub = lane & 7;        // 8 edges in flight (x2 unroll = 16)
  int f0  = (lane >> 3) * 4; // 8 float4 chunks -> 32 features
  int beg = rowptr[n], end = rowptr[n + 1];
  float4 acc = make_float4(0.f, 0.f, 0.f, 0.f);
  for (int k = beg + sub; k < end; k += 16) {
    int2 ca0 = colattr[k];
    int kb = k + 8;
    bool h1 = kb < end;
    int2 ca1 = h1 ? colattr[kb] : ca0;
    unsigned p0 = (unsigned)ca0.x, p1 = (unsigned)ca1.x;
    int s0 = (int)(p0 & 0xFFFFFu), g0 = (int)(p0 >> 20);
    int s1 = (int)(p1 & 0xFFFFFu), g1 = (int)(p1 >> 20);
    float a0 = __int_as_float(ca0.y), a1 = __int_as_float(ca1.y);
    float4 xv0 = *(const float4*)(x0 + (size_t)s0 * 32 + f0);
    float4 xv1 = *(const float4*)(x0 + (size_t)s1 * 32 + f0);
    float4 d0 = *(const float4*)&dt[g0 * 32 + f0];
    float4 c0 = *(const float4*)&ct[g0 * 32 + f0];
    float4 d1 = *(const float4*)&dt[g1 * 32 + f0];
    float4 c1 = *(const float4*)&ct[g1 * 32 + f0];
    acc.x += relu_(xv0.x + fmaf(a0, d0.x, c0.x));
    acc.y += relu_(xv0.y + fmaf(a0, d0.y, c0.y));
    acc.z += relu_(xv0.z + fmaf(a0, d0.z, c0.z));
    acc.w += relu_(xv0.w + fmaf(a0, d0.w, c0.w));
    if (h1) {
      acc.x += relu_(xv1.x + fmaf(a1, d1.x, c1.x));
      acc.y += relu_(xv1.y + fmaf(a1, d1.y, c1.y));
      acc.z += relu_(xv1.z + fmaf(a1, d1.z, c1.z));
      acc.w += relu_(xv1.w + fmaf(a1, d1.w, c1.w));
    }
  }
#pragma unroll
  for (int m = 1; m < 8; m <<= 1) {
    float4 o = shfl_xor4(acc, m);
    acc.x += o.x; acc.y += o.y; acc.z += o.z; acc.w += o.w;
  }
  if (sub == 0) {
    const float4 self = *(const float4*)(x0 + (size_t)n * 32 + f0);
    *(float4*)(hb + (size_t)n * 32 + f0) =
        make_float4(self.x + acc.x, self.y + acc.y, self.z + acc.z, self.w + acc.w);
  }
}

// conv2: sub=8 (8 edges in flight, x2 unroll = 16 gather pairs), each lane
// owns 8 features (two float4 loads per edge).
__global__ __launch_bounds__(256) void conv2_agg(
    const float* __restrict__ x1, const int* __restrict__ rowptr,
    const int2* __restrict__ colattr, const float* __restrict__ tabs, int enc,
    float* __restrict__ hb) {
  __shared__ float dt[NSEG * 64];
  __shared__ float ct[NSEG * 64];
  const float* d2 = tabs + TAB_E2 + (size_t)enc * 2 * NSEG * 64;
  for (int i = threadIdx.x; i < NSEG * 64; i += 256) {
    dt[i] = d2[i];
    ct[i] = d2[NSEG * 64 + i];
  }
  __syncthreads();
  int n = blockIdx.x * 4 + (threadIdx.x >> 6);  // grid exact: NN/4
  int lane = threadIdx.x & 63;
  int sub = lane & 7;        // 8 edges in flight (x2 unroll = 16)
  int f0  = (lane >> 3) * 8; // 8 features per lane -> 64 features
  int beg = rowptr[n], end = rowptr[n + 1];
  float4 accA = make_float4(0.f, 0.f, 0.f, 0.f);
  float4 accB = make_float4(0.f, 0.f, 0.f, 0.f);
  for (int k = beg + sub; k < end; k += 16) {
    int2 ca0 = colattr[k];
    int kb = k + 8;
    bool h1 = kb < end;
    int2 ca1 = h1 ? colattr[kb] : ca0;
    unsigned p0 = (unsigned)ca0.x, p1 = (unsigned)ca1.x;
    int s0 = (int)(p0 & 0xFFFFFu), g0 = (int)(p0 >> 20);
    int s1 = (int)(p1 & 0xFFFFFu), g1 = (int)(p1 >> 20);
    float a0 = __int_as_float(ca0.y), a1 = __int_as_float(ca1.y);
    const float* r0 = x1 + (size_t)s0 * 64 + f0;
    const float* r1 = x1 + (size_t)s1 * 64 + f0;
    float4 xa0 = *(const float4*)r0;
    float4 xb0 = *(const float4*)(r0 + 4);
    float4 xa1 = *(const float4*)r1;
    float4 xb1 = *(const float4*)(r1 + 4);
    float4 da0 = *(const float4*)&dt[g0 * 64 + f0];
    float4 db0 = *(const float4*)&dt[g0 * 64 + f0 + 4];
    float4 ea0 = *(const float4*)&ct[g0 * 64 + f0];
    float4 eb0 = *(const float4*)&ct[g0 * 64 + f0 + 4];
    accA.x += relu_(xa0.x + fmaf(a0, da0.x, ea0.x));
    accA.y += relu_(xa0.y + fmaf(a0, da0.y, ea0.y));
    accA.z += relu_(xa0.z + fmaf(a0, da0.z, ea0.z));
    accA.w += relu_(xa0.w + fmaf(a0, da0.w, ea0.w));
    accB.x += relu_(xb0.x + fmaf(a0, db0.x, eb0.x));
    accB.y += relu_(xb0.y + fmaf(a0, db0.y, eb0.y));
    accB.z += relu_(xb0.z + fmaf(a0, db0.z, eb0.z));
    accB.w += relu_(xb0.w + fmaf(a0, db0.w, eb0.w));
    if (h1) {
      float4 da1 = *(const float4*)&dt[g1 * 64 + f0];
      float4 db1 = *(const float4*)&dt[g1 * 64 + f0 + 4];
      float4 ea1 = *(const float4*)&ct[g1 * 64 + f0];
      float4 eb1 = *(const float4*)&ct[g1 * 64 + f0 + 4];
      accA.x += relu_(xa1.x + fmaf(a1, da1.x, ea1.x));
      accA.y += relu_(xa1.y + fmaf(a1, da1.y, ea1.y));
      accA.z += relu_(xa1.z + fmaf(a1, da1.z, ea1.z));
      accA.w += relu_(xa1.w + fmaf(a1, da1.w, ea1.w));
      accB.x += relu_(xb1.x + fmaf(a1, db1.x, eb1.x));
      accB.y += relu_(xb1.y + fmaf(a1, db1.y, eb1.y));
      accB.z += relu_(xb1.z + fmaf(a1, db1.z, eb1.z));
      accB.w += relu_(xb1.w + fmaf(a1, db1.w, eb1.w));
    }
  }
#pragma unroll
  for (int m = 1; m < 8; m <<= 1) {
    float4 oA = shfl_xor4(accA, m);
    float4 oB = shfl_xor4(accB, m);
    accA.x += oA.x; accA.y += oA.y; accA.z += oA.z; accA.w += oA.w;
    accB.x += oB.x; accB.y += oB.y; accB.z += oB.z; accB.w += oB.w;
  }
  if (sub == 0) {
    const float* sp = x1 + (size_t)n * 64 + f0;
    const float4 sA = *(const float4*)sp;
    const float4 sB = *(const float4*)(sp + 4);
    float* op = hb + (size_t)n * 64 + f0;
    *(float4*)op       = make_float4(sA.x + accA.x, sA.y + accA.y, sA.z + accA.z, sA.w + accA.w);
    *(float4*)(op + 4) = make_float4(sB.x + accB.x, sB.y + accB.y, sB.z + accB.z, sB.w + accB.w);
  }
}

// ---------------------------------------------------------------------------
// Per-node MLP2 (IN -> 64 -> 64), relu on both layers + output (conv wrapper).
// Register-tiled VALU GEMM: 64 nodes/block, thread owns 4 nodes x 4 features.
// ---------------------------------------------------------------------------
template <int IN>
__global__ __launch_bounds__(256) void node_mlp_tile(
    const float* __restrict__ hin,
    const float* __restrict__ W1, const float* __restrict__ b1,
    const float* __restrict__ W2, const float* __restrict__ b2,
    float* __restrict__ xout) {
  __shared__ float hsT[IN][65];   // [k][node], stride 65 -> conflict-free
  __shared__ float ysT[64][65];   // [feature][node]
  int base = blockIdx.x * 64;
  int count = NN - base; if (count > 64) count = 64;
  for (int idx = threadIdx.x; idx < 64 * IN; idx += 256) {
    int node = idx / IN, k = idx - node * IN;
    float v = (node < count) ? hin[(size_t)(base + node) * IN + k] : 0.0f;
    hsT[k][node] = v;
  }
  __syncthreads();
  int nt = threadIdx.x >> 4;   // node quad [0,16)
  int jx = threadIdx.x & 15;   // feature quad [0,16)
  int n0 = nt * 4, f0 = jx * 4;
  float4 acc0, acc1, acc2, acc3;
  {
    const float4 b = *(const float4*)(b1 + f0);
    acc0 = b; acc1 = b; acc2 = b; acc3 = b;
  }
  for (int k = 0; k < IN; ++k) {
    const float4 h = *(const float4*)&hsT[k][n0];
    const float4 w = *(const float4*)(W1 + k * 64 + f0);
    acc0.x = fmaf(h.x, w.x, acc0.x); acc0.y = fmaf(h.x, w.y, acc0.y);
    acc0.z = fmaf(h.x, w.z, acc0.z); acc0.w = fmaf(h.x, w.w, acc0.w);
    acc1.x = fmaf(h.y, w.x, acc1.x); acc1.y = fmaf(h.y, w.y, acc1.y);
    acc1.z = fmaf(h.y, w.z, acc1.z); acc1.w = fmaf(h.y, w.w, acc1.w);
    acc2.x = fmaf(h.z, w.x, acc2.x); acc2.y = fmaf(h.z, w.y, acc2.y);
    acc2.z = fmaf(h.z, w.z, acc2.z); acc2.w = fmaf(h.z, w.w, acc2.w);
    acc3.x = fmaf(h.w, w.x, acc3.x); acc3.y = fmaf(h.w, w.y, acc3.y);
    acc3.z = fmaf(h.w, w.z, acc3.z); acc3.w = fmaf(h.w, w.w, acc3.w);
  }
  ysT[f0 + 0][n0 + 0] = relu_(acc0.x); ysT[f0 + 1][n0 + 0] = relu_(acc0.y);
  ysT[f0 + 2][n0 + 0] = relu_(acc0.z); ysT[f0 + 3][n0 + 0] = relu_(acc0.w);
  ysT[f0 + 0][n0 + 1] = relu_(acc1.x); ysT[f0 + 1][n0 + 1] = relu_(acc1.y);
  ysT[f0 + 2][n0 + 1] = relu_(acc1.z); ysT[f0 + 3][n0 + 1] = relu_(acc1.w);
  ysT[f0 + 0][n0 + 2] = relu_(acc2.x); ysT[f0 + 1][n0 + 2] = relu_(acc2.y);
  ysT[f0 + 2][n0 + 2] = relu_(acc2.z); ysT[f0 + 3][n0 + 2] = relu_(acc2.w);
  ysT[f0 + 0][n0 + 3] = relu_(acc3.x); ysT[f0 + 1][n0 + 3] = relu_(acc3.y);
  ysT[f0 + 2][n0 + 3] = relu_(acc3.z); ysT[f0 + 3][n0 + 3] = relu_(acc3.w);
  __syncthreads();
  {
    const float4 b = *(const float4*)(b2 + f0);
    acc0 = b; acc1 = b; acc2 = b; acc3 = b;
  }
  for (int k = 0; k < 64; ++k) {
    const float4 h = *(const float4*)&ysT[k][n0];
    const float4 w = *(const float4*)(W2 + k * 64 + f0);
    acc0.x = fmaf(h.x, w.x, acc0.x); acc0.y = fmaf(h.x, w.y, acc0.y);
    acc0.z = fmaf(h.x, w.z, acc0.z); acc0.w = fmaf(h.x, w.w, acc0.w);
    acc1.x = fmaf(h.y, w.x, acc1.x); acc1.y = fmaf(h.y, w.y, acc1.y);
    acc1.z = fmaf(h.y, w.z, acc1.z); acc1.w = fmaf(h.y, w.w, acc1.w);
    acc2.x = fmaf(h.z, w.x, acc2.x); acc2.y = fmaf(h.z, w.y, acc2.y);
    acc2.z = fmaf(h.z, w.z, acc2.z); acc2.w = fmaf(h.z, w.w, acc2.w);
    acc3.x = fmaf(h.w, w.x, acc3.x); acc3.y = fmaf(h.w, w.y, acc3.y);
    acc3.z = fmaf(h.w, w.z, acc3.z); acc3.w = fmaf(h.w, w.w, acc3.w);
  }
  float4 o;
  if (0 < count - n0) {
    o = make_float4(relu_(acc0.x), relu_(acc0.y), relu_(acc0.z), relu_(acc0.w));
    *(float4*)(xout + (size_t)(base + n0 + 0) * 64 + f0) = o;
  }
  if (1 < count - n0) {
    o = make_float4(relu_(acc1.x), relu_(acc1.y), relu_(acc1.z), relu_(acc1.w));
    *(float4*)(xout + (size_t)(base + n0 + 1) * 64 + f0) = o;
  }
  if (2 < count - n0) {
    o = make_float4(relu_(acc2.x), relu_(acc2.y), relu_(acc2.z), relu_(acc2.w));
    *(float4*)(xout + (size_t)(base + n0 + 2) * 64 + f0) = o;
  }
  if (3 < count - n0) {
    o = make_float4(relu_(acc3.x), relu_(acc3.y), relu_(acc3.z), relu_(acc3.w));
    *(float4*)(xout + (size_t)(base + n0 + 3) * 64 + f0) = o;
  }
}

// ---------------------------------------------------------------------------
// Batch boundaries from the SORTED batch array (no atomics).
// ---------------------------------------------------------------------------
__global__ __launch_bounds__(256) void batch_bounds_dual(
    const int* __restrict__ bat_s, const int* __restrict__ bat_g,
    int* __restrict__ start_s, int* __restrict__ start_g) {
  int half = blockIdx.x >= 391;
  const int* bat = half ? bat_g : bat_s;
  int* start = half ? start_g : start_s;
  int i = (blockIdx.x - half * 391) * 256 + threadIdx.x;
  if (i >= NN) return;
  int cur = bat[i];
  int prev = (i == 0) ? -1 : bat[i - 1];
  for (int b = prev + 1; b <= cur; ++b) start[b] = i;
  if (i == NN - 1) {
    for (int b = cur + 1; b <= NBAT; ++b) start[b] = NN;
  }
}

__global__ __launch_bounds__(256) void pool_mean(
    const float* __restrict__ x2, const int* __restrict__ start, float* __restrict__ pool) {
  __shared__ float s[4][64];
  int g = blockIdx.x;
  int f = threadIdx.x & 63, c = threadIdx.x >> 6;
  int beg = start[g], end = start[g + 1];
  float acc = 0.0f;
  for (int n = beg + c; n < end; n += 4) acc += x2[(size_t)n * 64 + f];
  s[c][f] = acc;
  __syncthreads();
  if (c == 0) {
    float tot = s[0][f] + s[1][f] + s[2][f] + s[3][f];
    float m = (float)(end - beg);
    pool[g * 64 + f] = tot / fmaxf(m, 1.0f);
  }
}

// ---------------------------------------------------------------------------
// regressor: out[b] = relu([s|g|depth] @ rW1 + rb1) @ rW2 + rb2
// ---------------------------------------------------------------------------
__global__ __launch_bounds__(256) void regressor16(
    const float* __restrict__ ps, const float* __restrict__ pg, const float* __restrict__ depth,
    const float* __restrict__ W1, const float* __restrict__ b1,
    const float* __restrict__ W2, const float* __restrict__ b2,
    float* __restrict__ out) {
  __shared__ float zs[16][132];   // [row][k], k in [0,129)
  __shared__ float ys[64][17];
  int base = blockIdx.x * 16;     // grid 32 blocks x 16 rows = 512 exact
  for (int i = threadIdx.x; i < 16 * 64; i += 256) {
    int ln = i >> 6, k = i & 63;
    zs[ln][k]      = ps[(size_t)(base + ln) * 64 + k];
    zs[ln][64 + k] = pg[(size_t)(base + ln) * 64 + k];
  }
  if (threadIdx.x < 16) zs[threadIdx.x][128] = depth[base + threadIdx.x];
  __syncthreads();
  int g = threadIdx.x >> 4;
  int j = threadIdx.x & 15;
  int f0 = j * 4;
  float a0, a1, a2, a3;
  {
    const float4 b = *(const float4*)(b1 + f0);
    a0 = b.x; a1 = b.y; a2 = b.z; a3 = b.w;
  }
  for (int k = 0; k < 129; ++k) {
    float zv = zs[g][k];
    const float4 w = *(const float4*)(W1 + k * 64 + f0);
    a0 = fmaf(zv, w.x, a0); a1 = fmaf(zv, w.y, a1);
    a2 = fmaf(zv, w.z, a2); a3 = fmaf(zv, w.w, a3);
  }
  ys[f0 + 0][g] = relu_(a0);
  ys[f0 + 1][g] = relu_(a1);
  ys[f0 + 2][g] = relu_(a2);
  ys[f0 + 3][g] = relu_(a3);
  __syncthreads();
  float s = ys[f0 + 0][g] * W2[f0 + 0] + ys[f0 + 1][g] * W2[f0 + 1] +
            ys[f0 + 2][g] * W2[f0 + 2] + ys[f0 + 3][g] * W2[f0 + 3];
#pragma unroll
  for (int m = 1; m < 16; m <<= 1) s += __shfl_xor(s, m);
  if (j == 0) out[base + g] = s + b2[0];
}

}  // namespace

extern "C" void kernel_launch(void* const* d_in, const int* in_sizes, int n_in,
                              void* d_out, int out_size, void* d_ws, size_t ws_size,
                              hipStream_t stream) {
  const int*   names_s = (const int*)d_in[0];
  const int*   ei_s    = (const int*)d_in[1];
  const float* ea_s    = (const float*)d_in[2];
  const int*   bat_s   = (const int*)d_in[3];
  const int*   names_g = (const int*)d_in[4];
  const int*   ei_g    = (const int*)d_in[5];
  const float* ea_g    = (const float*)d_in[6];
  const int*   bat_g   = (const int*)d_in[7];
  const float* depth   = (const float*)d_in[8];
  const float* idW1 = (const float*)d_in[9],  *idb1 = (const float*)d_in[10];
  const float* idW2 = (const float*)d_in[11], *idb2 = (const float*)d_in[12];
  const float* edW1 = (const float*)d_in[13], *edb1 = (const float*)d_in[14];
  const float* edW2 = (const float*)d_in[15], *edb2 = (const float*)d_in[16];
  const float* s1W1 = (const float*)d_in[17], *s1b1 = (const float*)d_in[18];
  const float* s1W2 = (const float*)d_in[19], *s1b2 = (const float*)d_in[20];
  const float* s2W1 = (const float*)d_in[21], *s2b1 = (const float*)d_in[22];
  const float* s2W2 = (const float*)d_in[23], *s2b2 = (const float*)d_in[24];
  const float* s2LW = (const float*)d_in[25], *s2Lb = (const float*)d_in[26];
  const float* g1W1 = (const float*)d_in[27], *g1b1 = (const float*)d_in[28];
  const float* g1W2 = (const float*)d_in[29], *g1b2 = (const float*)d_in[30];
  const float* g2W1 = (const float*)d_in[31], *g2b1 = (const float*)d_in[32];
  const float* g2W2 = (const float*)d_in[33], *g2b2 = (const float*)d_in[34];
  const float* g2LW = (const float*)d_in[35], *g2Lb = (const float*)d_in[36];
  const float* rW1  = (const float*)d_in[37], *rb1  = (const float*)d_in[38];
  const float* rW2  = (const float*)d_in[39], *rb2  = (const float*)d_in[40];
  (void)in_sizes; (void)n_in; (void)out_size; (void)ws_size;

  char* ws = (char*)d_ws;
  size_t off = 0;
  auto alloc = [&](size_t bytes) -> char* {
    char* p = ws + off;
    off += (bytes + 255) & ~(size_t)255;
    return p;
  };
  float* tabs    = (float*)alloc((size_t)TAB_TOTAL * 4);
  // bufA/bufB (x and h activations, 51.2 MB) alias the bucket scratch:
  // buckets are fully consumed by bucket_to_csr before node_embed writes bufA.
  char*  bigreg  = alloc((size_t)2 * NN * 64 * 4);          // 51,200,000 B
  float* bufA    = (float*)bigreg;
  float* bufB    = (float*)(bigreg + (size_t)NN * 64 * 4);
  int2*  bucket_mem = (int2*)bigreg;                        // NBUK*BCAP*8 = 51,200,000 B
  int2*  colattr = (int2*) alloc((size_t)2 * NEDG * 8);     // both graphs, CSR order
  int*   bcnt    = (int*)  alloc((size_t)NBUK * 8 * 4);     // per-sub-bucket counters
  int*   bbase   = (int*)  alloc((size_t)NBUK * 4);
  int*   rowptr  = (int*)  alloc((size_t)(2 * NN + 1) * 4);
  int*   start_s = (int*)  alloc((size_t)(NBAT + 1) * 4);
  int*   start_g = (int*)  alloc((size_t)(NBAT + 1) * 4);
  float* pool_s  = (float*)alloc((size_t)NBAT * 64 * 4);
  float* pool_g  = (float*)alloc((size_t)NBAT * 64 * 4);

  build_tables<<<1, 256, 0, stream>>>(edW1, edb1, edW2, edb2, s2LW, s2Lb, g2LW, g2Lb, tabs);

  // --- bucketed CSR build for BOTH graphs (dense-line writes, no global hist)
  hipMemsetAsync(bcnt, 0, (size_t)NBUK * 8 * 4, stream);
  bucket_scatter<<<EBLK, 256, 0, stream>>>(ei_s, ei_s + NEDG, ea_s,
                                           ei_g, ei_g + NEDG, ea_g,
                                           bcnt, bucket_mem);
  bucket_scan<<<1, 1024, 0, stream>>>(bcnt, bbase, rowptr);
  bucket_to_csr<<<NBUK, 256, 0, stream>>>(bcnt, bbase, bucket_mem, tabs, rowptr, colattr);
  batch_bounds_dual<<<782, 256, 0, stream>>>(bat_s, bat_g, start_s, start_g);

  auto encoder = [&](const int* names, const int* start, const int* rp,
                     const float* c1W1, const float* c1b1, const float* c1W2, const float* c1b2,
                     const float* c2W1, const float* c2b1, const float* c2W2, const float* c2b2,
                     int enc, float* pool) {
    node_embed<<<391, 256, 0, stream>>>(names, idW1, idb1, idW2, idb2, bufA);
    conv1_agg<<<NN / 4, 256, 0, stream>>>(bufA, rp, colattr, tabs, bufB);
    node_mlp_tile<32><<<(NN + 63) / 64, 256, 0, stream>>>(bufB, c1W1, c1b1, c1W2, c1b2, bufA);
    conv2_agg<<<NN / 4, 256, 0, stream>>>(bufA, rp, colattr, tabs, enc, bufB);
    node_mlp_tile<64><<<(NN + 63) / 64, 256, 0, stream>>>(bufB, c2W1, c2b1, c2W2, c2b2, bufA);
    pool_mean<<<NBAT, 256, 0, stream>>>(bufA, start, pool);
  };

  encoder(names_s, start_s, rowptr,      s1W1, s1b1, s1W2, s1b2, s2W1, s2b1, s2W2, s2b2, 0, pool_s);
  encoder(names_g, start_g, rowptr + NN, g1W1, g1b1, g1W2, g1b2, g2W1, g2b1, g2W2, g2b2, 1, pool_g);

  regressor16<<<32, 256, 0, stream>>>(pool_s, pool_g, depth, rW1, rb1, rW2, rb2, (float*)d_out);
}

// Round 8
// 829.129 us; speedup vs baseline: 1.8101x; 1.1521x over previous
//
#include <hip/hip_runtime.h>
#include <stdint.h>

namespace {

constexpr int NN   = 100000;    // nodes per graph
constexpr int NEDG = 1600000;   // edges per graph
constexpr int TE   = 2 * NEDG;  // 3.2M edges across both graphs
constexpr int NBAT = 512;       // graphs per batch
constexpr int NSEG = 33;        // piecewise-linear segments of edge MLP (32 breakpoints)

// coarse partition: 256 dst-nodes per coarse bucket
constexpr int NC     = 782;     // ceil(2*NN / 256)
constexpr int TILE   = 4096;    // edges per partition block (16 per thread)
constexpr int ABLK   = (TE + TILE - 1) / TILE;  // 782
constexpr int ENTCAP = 5120;    // max entries per coarse bucket (mean 4096, +16 sigma)

// table layout (floats): bp[32] | d1[NSEG*32] | c1[NSEG*32] | per-enc {d2[NSEG*64], c2[NSEG*64]} x2
constexpr int TAB_BP = 0;
constexpr int TAB_D1 = 32;
constexpr int TAB_C1 = TAB_D1 + NSEG * 32;
constexpr int TAB_E2 = TAB_C1 + NSEG * 32;
constexpr int TAB_TOTAL = TAB_E2 + 4 * NSEG * 64;

__device__ __forceinline__ float relu_(float x) { return fmaxf(x, 0.0f); }

__device__ __forceinline__ float4 shfl_xor4(float4 v, int m) {
  return make_float4(__shfl_xor(v.x, m), __shfl_xor(v.y, m),
                     __shfl_xor(v.z, m), __shfl_xor(v.w, m));
}

// ---------------------------------------------------------------------------
// Precompute piecewise-linear tables for e(a) = relu(a*W1+b1)@W2+b2 and the
// folded e2(a) = e(a)@linW + linb. Exact reassociation of the reference math.
// ---------------------------------------------------------------------------
__global__ void build_tables(const float* __restrict__ eW1, const float* __restrict__ eb1,
                             const float* __restrict__ eW2, const float* __restrict__ eb2,
                             const float* __restrict__ sLW, const float* __restrict__ sLb,
                             const float* __restrict__ gLW, const float* __restrict__ gLb,
                             float* __restrict__ tabs) {
  __shared__ float traw[32];
  __shared__ float ts[32];
  __shared__ float dt[NSEG * 32];
  __shared__ float ct[NSEG * 32];
  int tid = threadIdx.x;
  if (tid < 32) {
    float w = eW1[tid], b = eb1[tid];
    traw[tid] = (w != 0.0f) ? (-b / w) : 3.0e38f;
  }
  __syncthreads();
  if (tid < 32) {  // rank sort (stable for duplicates)
    float v = traw[tid];
    int r = 0;
    for (int j = 0; j < 32; ++j) {
      float u = traw[j];
      r += (u < v) || (u == v && j < tid);
    }
    ts[r] = v;
  }
  __syncthreads();
  if (tid < 32) tabs[TAB_BP + tid] = ts[tid];
  for (int idx = tid; idx < NSEG * 32; idx += blockDim.x) {
    int s = idx >> 5, j = idx & 31;
    float a;  // representative point strictly inside segment s: (ts[s-1], ts[s]]
    if (s == 0)            a = ts[0] - 1.0f;
    else if (s == NSEG - 1) a = ts[31] + 1.0f;
    else                   a = 0.5f * ts[s - 1] + 0.5f * ts[s];
    float d = 0.0f, c = 0.0f;
    for (int i = 0; i < 32; ++i) {
      float w = eW1[i], b = eb1[i];
      if (fmaf(a, w, b) > 0.0f) {
        float w2 = eW2[i * 32 + j];
        d = fmaf(w, w2, d);
        c = fmaf(b, w2, c);
      }
    }
    c += eb2[j];
    dt[idx] = d; ct[idx] = c;
    tabs[TAB_D1 + idx] = d;
    tabs[TAB_C1 + idx] = c;
  }
  __syncthreads();
  for (int idx = tid; idx < NSEG * 64; idx += blockDim.x) {
    int s = idx >> 6, k = idx & 63;
    float ds = 0.f, cs = 0.f, dg = 0.f, cg = 0.f;
    for (int j = 0; j < 32; ++j) {
      float dv = dt[s * 32 + j], cv = ct[s * 32 + j];
      float ws = sLW[j * 64 + k], wg = gLW[j * 64 + k];
      ds = fmaf(dv, ws, ds); cs = fmaf(cv, ws, cs);
      dg = fmaf(dv, wg, dg); cg = fmaf(cv, wg, cg);
    }
    cs += sLb[k]; cg += gLb[k];
    tabs[TAB_E2 + idx]                 = ds;
    tabs[TAB_E2 + NSEG * 64 + idx]     = cs;
    tabs[TAB_E2 + 2 * NSEG * 64 + idx] = dg;
    tabs[TAB_E2 + 3 * NSEG * 64 + idx] = cg;
  }
}

// ---------------------------------------------------------------------------
// x0[n,32] = MLP2(clip((names+2)/SCALE,0,1))
// ---------------------------------------------------------------------------
__global__ __launch_bounds__(256, 2) void node_embed(
    const int* __restrict__ names,
    const float* __restrict__ W1, const float* __restrict__ b1,
    const float* __restrict__ W2, const float* __restrict__ b2,
    float* __restrict__ x0) {
  int n = blockIdx.x * 256 + threadIdx.x;
  if (n >= NN) return;
  float norm = ((float)names[n] + 2.0f) / 281474976710655.0f;
  norm = fminf(fmaxf(norm, 0.0f), 1.0f);
  float h[32];
#pragma unroll
  for (int i = 0; i < 32; ++i) h[i] = relu_(fmaf(norm, W1[i], b1[i]));
  float4* out = (float4*)(x0 + (size_t)n * 32);
  for (int j0 = 0; j0 < 32; j0 += 4) {
    float a0 = b2[j0], a1 = b2[j0 + 1], a2 = b2[j0 + 2], a3 = b2[j0 + 3];
#pragma unroll
    for (int i = 0; i < 32; ++i) {
      float hv = h[i];
      a0 = fmaf(hv, W2[i * 32 + j0],     a0);
      a1 = fmaf(hv, W2[i * 32 + j0 + 1], a1);
      a2 = fmaf(hv, W2[i * 32 + j0 + 2], a2);
      a3 = fmaf(hv, W2[i * 32 + j0 + 3], a3);
    }
    out[j0 >> 2] = make_float4(a0, a1, a2, a3);
  }
}

// ---------------------------------------------------------------------------
// CSR build, dense-write edition. Rounds 2-7 all measured ~7x write
// amplification for scattered 8B stores (each small store costs a full 64B
// HBM line, regardless of XCD-locality scheme). Fix: stage/reorder in LDS so
// every global write is a contiguous run.
//   Entry in part[]: {src | dlocal<<17, attr_bits}, dlocal = dstGlobal & 255.
// ---------------------------------------------------------------------------
__global__ __launch_bounds__(256) void coarse_hist(
    const int* __restrict__ dst_s, const int* __restrict__ dst_g,
    int* __restrict__ ccnt) {
  __shared__ int h[NC];
  for (int i = threadIdx.x; i < NC; i += 256) h[i] = 0;
  __syncthreads();
  int base = blockIdx.x * TILE;
#pragma unroll
  for (int j = 0; j < 16; ++j) {
    int i = base + j * 256 + threadIdx.x;
    if (i < TE) {
      int d = (i < NEDG) ? dst_s[i] : (dst_g[i - NEDG] + NN);
      atomicAdd(&h[d >> 8], 1);
    }
  }
  __syncthreads();
  for (int i = threadIdx.x; i < NC; i += 256)
    if (h[i]) atomicAdd(&ccnt[i], h[i]);
}

__global__ __launch_bounds__(1024) void coarse_scan(
    const int* __restrict__ ccnt, int* __restrict__ cbase,
    int* __restrict__ gcur, int* __restrict__ rowptr) {
  __shared__ int s[1024];
  int t = threadIdx.x;
  int v = (t < NC) ? ccnt[t] : 0;
  s[t] = v;
  __syncthreads();
  for (int st = 1; st < 1024; st <<= 1) {
    int u = (t >= st) ? s[t - st] : 0;
    __syncthreads();
    s[t] += u;
    __syncthreads();
  }
  if (t < NC) { cbase[t] = s[t] - v; gcur[t] = s[t] - v; }
  if (t == 0) rowptr[2 * NN] = TE;
}

// Per 4096-edge tile: LDS hist -> LDS scan -> one global reservation per
// (block,bin) -> reorder entries into LDS (sorted by bin) -> flush runs.
// Runs avg ~5 entries; flush is contiguous per run (write amp ~2x, not 7x).
__global__ __launch_bounds__(256) void coarse_partition(
    const int* __restrict__ src_s, const int* __restrict__ dst_s, const float* __restrict__ attr_s,
    const int* __restrict__ src_g, const int* __restrict__ dst_g, const float* __restrict__ attr_g,
    int* __restrict__ gcur, int2* __restrict__ part) {
  __shared__ int hist[NC];      // counts, then overwritten with global base
  __shared__ int lofs[NC];
  __shared__ int lcur[NC];
  __shared__ int2 sorted[TILE]; // 32 KB
  __shared__ int addr[TILE];    // 16 KB
  __shared__ int scanbuf[256];
  int t = threadIdx.x;
  for (int i = t; i < NC; i += 256) hist[i] = 0;
  __syncthreads();
  int base = blockIdx.x * TILE;
#pragma unroll
  for (int j = 0; j < 16; ++j) {
    int i = base + j * 256 + t;
    if (i < TE) {
      int d = (i < NEDG) ? dst_s[i] : (dst_g[i - NEDG] + NN);
      atomicAdd(&hist[d >> 8], 1);
    }
  }
  __syncthreads();
  // exclusive scan of hist[NC]: thread t owns bins [4t, 4t+4)
  int loc[4];
  int sum = 0;
#pragma unroll
  for (int j = 0; j < 4; ++j) {
    int b = t * 4 + j;
    int v = (b < NC) ? hist[b] : 0;
    loc[j] = sum; sum += v;
  }
  scanbuf[t] = sum;
  __syncthreads();
  for (int st = 1; st < 256; st <<= 1) {
    int u = (t >= st) ? scanbuf[t - st] : 0;
    __syncthreads();
    scanbuf[t] += u;
    __syncthreads();
  }
  int texcl = scanbuf[t] - sum;
#pragma unroll
  for (int j = 0; j < 4; ++j) {
    int b = t * 4 + j;
    if (b < NC) { lofs[b] = texcl + loc[j]; lcur[b] = 0; }
  }
  __syncthreads();
  // reserve global space per non-empty bin; hist becomes the global base
  for (int b = t; b < NC; b += 256) {
    int c = hist[b];
    hist[b] = c ? atomicAdd(&gcur[b], c) : 0;
  }
  __syncthreads();
  // place entries into bin-sorted LDS staging, record global addresses
#pragma unroll
  for (int j = 0; j < 16; ++j) {
    int i = base + j * 256 + t;
    if (i < TE) {
      int sl, d; float a;
      if (i < NEDG) { sl = src_s[i]; d = dst_s[i]; a = attr_s[i]; }
      else { int k = i - NEDG; sl = src_g[k]; d = dst_g[k] + NN; a = attr_g[k]; }
      int c = d >> 8;
      int r = atomicAdd(&lcur[c], 1);
      int s = lofs[c] + r;
      sorted[s] = make_int2(sl | ((d & 255) << 17), __float_as_int(a));
      addr[s] = hist[c] + r;
    }
  }
  __syncthreads();
  int tot = (base + TILE <= TE) ? TILE : (TE - base);
  for (int s = t; s < tot; s += 256) part[addr[s]] = sorted[s];
}

// One block per coarse bucket: 256-bin LDS hist/scan -> rowptr (plain
// stores), scatter into LDS outE, then fully dense copy to colattr.
__global__ __launch_bounds__(256) void partition_to_csr(
    const int* __restrict__ ccnt, const int* __restrict__ cbase,
    const int2* __restrict__ part, const float* __restrict__ tabs,
    int* __restrict__ rowptr, int2* __restrict__ colattr) {
  __shared__ int2 outE[ENTCAP];  // 40 KB
  __shared__ int hist[256];
  __shared__ int cur[256];
  __shared__ int sc[256];
  __shared__ float bp[32];
  int t = threadIdx.x, b = blockIdx.x;  // grid exact: NC
  if (t < 32) bp[t] = tabs[TAB_BP + t];
  hist[t] = 0;
  __syncthreads();
  int cnt = ccnt[b], base = cbase[b];
  for (int i = t; i < cnt; i += 256)
    atomicAdd(&hist[(part[base + i].x >> 17) & 255], 1);
  __syncthreads();
  int v = hist[t];
  sc[t] = v;
  __syncthreads();
  for (int st = 1; st < 256; st <<= 1) {
    int u = (t >= st) ? sc[t - st] : 0;
    __syncthreads();
    sc[t] += u;
    __syncthreads();
  }
  int excl = sc[t] - v;
  int gnode = b * 256 + t;
  if (gnode < 2 * NN) rowptr[gnode] = base + excl;
  cur[t] = excl;
  __syncthreads();
  for (int i = t; i < cnt; i += 256) {
    int2 e = part[base + i];
    int dl = (e.x >> 17) & 255;
    int srcn = e.x & 0x1FFFF;
    float a = __int_as_float(e.y);
    int seg = 0;
#pragma unroll
    for (int k = 0; k < 32; ++k) seg += (bp[k] < a);
    int pos = atomicAdd(&cur[dl], 1);
    outE[pos] = make_int2(srcn | (seg << 20), e.y);  // src<2^17, seg<64
  }
  __syncthreads();
  for (int i = t; i < cnt; i += 256) colattr[base + i] = outE[i];
}

// ---------------------------------------------------------------------------
// GINE aggregation, dst-major. One WAVE per node; wave processes several
// edges concurrently (sub = edge slot) so 16 row gathers are in flight per
// wave. hb[n] = x[n] + sum_j relu(x[src_j] + e_j). src ids are graph-local.
// ---------------------------------------------------------------------------
__global__ __launch_bounds__(256) void conv1_agg(
    const float* __restrict__ x0, const int* __restrict__ rowptr,
    const int2* __restrict__ colattr, const float* __restrict__ tabs,
    float* __restrict__ hb) {
  __shared__ float dt[NSEG * 32];
  __shared__ float ct[NSEG * 32];
  for (int i = threadIdx.x; i < NSEG * 32; i += 256) {
    dt[i] = tabs[TAB_D1 + i];
    ct[i] = tabs[TAB_C1 + i];
  }
  __syncthreads();
  int n = blockIdx.x * 4 + (threadIdx.x >> 6);  // grid exact: NN/4
  int lane = threadIdx.x & 63;
  int sub = lane & 7;        // 8 edges in flight (x2 unroll = 16)
  int f0  = (lane >> 3) * 4; // 8 float4 chunks -> 32 features
  int beg = rowptr[n], end = rowptr[n + 1];
  float4 acc = make_float4(0.f, 0.f, 0.f, 0.f);
  for (int k = beg + sub; k < end; k += 16) {
    int2 ca0 = colattr[k];
    int kb = k + 8;
    bool h1 = kb < end;
    int2 ca1 = h1 ? colattr[kb] : ca0;
    unsigned p0 = (unsigned)ca0.x, p1 = (unsigned)ca1.x;
    int s0 = (int)(p0 & 0xFFFFFu), g0 = (int)(p0 >> 20);
    int s1 = (int)(p1 & 0xFFFFFu), g1 = (int)(p1 >> 20);
    float a0 = __int_as_float(ca0.y), a1 = __int_as_float(ca1.y);
    float4 xv0 = *(const float4*)(x0 + (size_t)s0 * 32 + f0);
    float4 xv1 = *(const float4*)(x0 + (size_t)s1 * 32 + f0);
    float4 d0 = *(const float4*)&dt[g0 * 32 + f0];
    float4 c0 = *(const float4*)&ct[g0 * 32 + f0];
    float4 d1 = *(const float4*)&dt[g1 * 32 + f0];
    float4 c1 = *(const float4*)&ct[g1 * 32 + f0];
    acc.x += relu_(xv0.x + fmaf(a0, d0.x, c0.x));
    acc.y += relu_(xv0.y + fmaf(a0, d0.y, c0.y));
    acc.z += relu_(xv0.z + fmaf(a0, d0.z, c0.z));
    acc.w += relu_(xv0.w + fmaf(a0, d0.w, c0.w));
    if (h1) {
      acc.x += relu_(xv1.x + fmaf(a1, d1.x, c1.x));
      acc.y += relu_(xv1.y + fmaf(a1, d1.y, c1.y));
      acc.z += relu_(xv1.z + fmaf(a1, d1.z, c1.z));
      acc.w += relu_(xv1.w + fmaf(a1, d1.w, c1.w));
    }
  }
#pragma unroll
  for (int m = 1; m < 8; m <<= 1) {
    float4 o = shfl_xor4(acc, m);
    acc.x += o.x; acc.y += o.y; acc.z += o.z; acc.w += o.w;
  }
  if (sub == 0) {
    const float4 self = *(const float4*)(x0 + (size_t)n * 32 + f0);
    *(float4*)(hb + (size_t)n * 32 + f0) =
        make_float4(self.x + acc.x, self.y + acc.y, self.z + acc.z, self.w + acc.w);
  }
}

// conv2: sub=8 (8 edges in flight, x2 unroll = 16 gather pairs), each lane
// owns 8 features (two float4 loads per edge).
__global__ __launch_bounds__(256) void conv2_agg(
    const float* __restrict__ x1, const int* __restrict__ rowptr,
    const int2* __restrict__ colattr, const float* __restrict__ tabs, int enc,
    float* __restrict__ hb) {
  __shared__ float dt[NSEG * 64];
  __shared__ float ct[NSEG * 64];
  const float* d2 = tabs + TAB_E2 + (size_t)enc * 2 * NSEG * 64;
  for (int i = threadIdx.x; i < NSEG * 64; i += 256) {
    dt[i] = d2[i];
    ct[i] = d2[NSEG * 64 + i];
  }
  __syncthreads();
  int n = blockIdx.x * 4 + (threadIdx.x >> 6);  // grid exact: NN/4
  int lane = threadIdx.x & 63;
  int sub = lane & 7;        // 8 edges in flight (x2 unroll = 16)
  int f0  = (lane >> 3) * 8; // 8 features per lane -> 64 features
  int beg = rowptr[n], end = rowptr[n + 1];
  float4 accA = make_float4(0.f, 0.f, 0.f, 0.f);
  float4 accB = make_float4(0.f, 0.f, 0.f, 0.f);
  for (int k = beg + sub; k < end; k += 16) {
    int2 ca0 = colattr[k];
    int kb = k + 8;
    bool h1 = kb < end;
    int2 ca1 = h1 ? colattr[kb] : ca0;
    unsigned p0 = (unsigned)ca0.x, p1 = (unsigned)ca1.x;
    int s0 = (int)(p0 & 0xFFFFFu), g0 = (int)(p0 >> 20);
    int s1 = (int)(p1 & 0xFFFFFu), g1 = (int)(p1 >> 20);
    float a0 = __int_as_float(ca0.y), a1 = __int_as_float(ca1.y);
    const float* r0 = x1 + (size_t)s0 * 64 + f0;
    const float* r1 = x1 + (size_t)s1 * 64 + f0;
    float4 xa0 = *(const float4*)r0;
    float4 xb0 = *(const float4*)(r0 + 4);
    float4 xa1 = *(const float4*)r1;
    float4 xb1 = *(const float4*)(r1 + 4);
    float4 da0 = *(const float4*)&dt[g0 * 64 + f0];
    float4 db0 = *(const float4*)&dt[g0 * 64 + f0 + 4];
    float4 ea0 = *(const float4*)&ct[g0 * 64 + f0];
    float4 eb0 = *(const float4*)&ct[g0 * 64 + f0 + 4];
    accA.x += relu_(xa0.x + fmaf(a0, da0.x, ea0.x));
    accA.y += relu_(xa0.y + fmaf(a0, da0.y, ea0.y));
    accA.z += relu_(xa0.z + fmaf(a0, da0.z, ea0.z));
    accA.w += relu_(xa0.w + fmaf(a0, da0.w, ea0.w));
    accB.x += relu_(xb0.x + fmaf(a0, db0.x, eb0.x));
    accB.y += relu_(xb0.y + fmaf(a0, db0.y, eb0.y));
    accB.z += relu_(xb0.z + fmaf(a0, db0.z, eb0.z));
    accB.w += relu_(xb0.w + fmaf(a0, db0.w, eb0.w));
    if (h1) {
      float4 da1 = *(const float4*)&dt[g1 * 64 + f0];
      float4 db1 = *(const float4*)&dt[g1 * 64 + f0 + 4];
      float4 ea1 = *(const float4*)&ct[g1 * 64 + f0];
      float4 eb1 = *(const float4*)&ct[g1 * 64 + f0 + 4];
      accA.x += relu_(xa1.x + fmaf(a1, da1.x, ea1.x));
      accA.y += relu_(xa1.y + fmaf(a1, da1.y, ea1.y));
      accA.z += relu_(xa1.z + fmaf(a1, da1.z, ea1.z));
      accA.w += relu_(xa1.w + fmaf(a1, da1.w, ea1.w));
      accB.x += relu_(xb1.x + fmaf(a1, db1.x, eb1.x));
      accB.y += relu_(xb1.y + fmaf(a1, db1.y, eb1.y));
      accB.z += relu_(xb1.z + fmaf(a1, db1.z, eb1.z));
      accB.w += relu_(xb1.w + fmaf(a1, db1.w, eb1.w));
    }
  }
#pragma unroll
  for (int m = 1; m < 8; m <<= 1) {
    float4 oA = shfl_xor4(accA, m);
    float4 oB = shfl_xor4(accB, m);
    accA.x += oA.x; accA.y += oA.y; accA.z += oA.z; accA.w += oA.w;
    accB.x += oB.x; accB.y += oB.y; accB.z += oB.z; accB.w += oB.w;
  }
  if (sub == 0) {
    const float* sp = x1 + (size_t)n * 64 + f0;
    const float4 sA = *(const float4*)sp;
    const float4 sB = *(const float4*)(sp + 4);
    float* op = hb + (size_t)n * 64 + f0;
    *(float4*)op       = make_float4(sA.x + accA.x, sA.y + accA.y, sA.z + accA.z, sA.w + accA.w);
    *(float4*)(op + 4) = make_float4(sB.x + accB.x, sB.y + accB.y, sB.z + accB.z, sB.w + accB.w);
  }
}

// ---------------------------------------------------------------------------
// Per-node MLP2 (IN -> 64 -> 64), relu on both layers + output (conv wrapper).
// Register-tiled VALU GEMM: 64 nodes/block, thread owns 4 nodes x 4 features.
// ---------------------------------------------------------------------------
template <int IN>
__global__ __launch_bounds__(256) void node_mlp_tile(
    const float* __restrict__ hin,
    const float* __restrict__ W1, const float* __restrict__ b1,
    const float* __restrict__ W2, const float* __restrict__ b2,
    float* __restrict__ xout) {
  __shared__ float hsT[IN][65];   // [k][node], stride 65 -> conflict-free
  __shared__ float ysT[64][65];   // [feature][node]
  int base = blockIdx.x * 64;
  int count = NN - base; if (count > 64) count = 64;
  for (int idx = threadIdx.x; idx < 64 * IN; idx += 256) {
    int node = idx / IN, k = idx - node * IN;
    float v = (node < count) ? hin[(size_t)(base + node) * IN + k] : 0.0f;
    hsT[k][node] = v;
  }
  __syncthreads();
  int nt = threadIdx.x >> 4;   // node quad [0,16)
  int jx = threadIdx.x & 15;   // feature quad [0,16)
  int n0 = nt * 4, f0 = jx * 4;
  float4 acc0, acc1, acc2, acc3;
  {
    const float4 b = *(const float4*)(b1 + f0);
    acc0 = b; acc1 = b; acc2 = b; acc3 = b;
  }
  for (int k = 0; k < IN; ++k) {
    const float4 h = *(const float4*)&hsT[k][n0];
    const float4 w = *(const float4*)(W1 + k * 64 + f0);
    acc0.x = fmaf(h.x, w.x, acc0.x); acc0.y = fmaf(h.x, w.y, acc0.y);
    acc0.z = fmaf(h.x, w.z, acc0.z); acc0.w = fmaf(h.x, w.w, acc0.w);
    acc1.x = fmaf(h.y, w.x, acc1.x); acc1.y = fmaf(h.y, w.y, acc1.y);
    acc1.z = fmaf(h.y, w.z, acc1.z); acc1.w = fmaf(h.y, w.w, acc1.w);
    acc2.x = fmaf(h.z, w.x, acc2.x); acc2.y = fmaf(h.z, w.y, acc2.y);
    acc2.z = fmaf(h.z, w.z, acc2.z); acc2.w = fmaf(h.z, w.w, acc2.w);
    acc3.x = fmaf(h.w, w.x, acc3.x); acc3.y = fmaf(h.w, w.y, acc3.y);
    acc3.z = fmaf(h.w, w.z, acc3.z); acc3.w = fmaf(h.w, w.w, acc3.w);
  }
  ysT[f0 + 0][n0 + 0] = relu_(acc0.x); ysT[f0 + 1][n0 + 0] = relu_(acc0.y);
  ysT[f0 + 2][n0 + 0] = relu_(acc0.z); ysT[f0 + 3][n0 + 0] = relu_(acc0.w);
  ysT[f0 + 0][n0 + 1] = relu_(acc1.x); ysT[f0 + 1][n0 + 1] = relu_(acc1.y);
  ysT[f0 + 2][n0 + 1] = relu_(acc1.z); ysT[f0 + 3][n0 + 1] = relu_(acc1.w);
  ysT[f0 + 0][n0 + 2] = relu_(acc2.x); ysT[f0 + 1][n0 + 2] = relu_(acc2.y);
  ysT[f0 + 2][n0 + 2] = relu_(acc2.z); ysT[f0 + 3][n0 + 2] = relu_(acc2.w);
  ysT[f0 + 0][n0 + 3] = relu_(acc3.x); ysT[f0 + 1][n0 + 3] = relu_(acc3.y);
  ysT[f0 + 2][n0 + 3] = relu_(acc3.z); ysT[f0 + 3][n0 + 3] = relu_(acc3.w);
  __syncthreads();
  {
    const float4 b = *(const float4*)(b2 + f0);
    acc0 = b; acc1 = b; acc2 = b; acc3 = b;
  }
  for (int k = 0; k < 64; ++k) {
    const float4 h = *(const float4*)&ysT[k][n0];
    const float4 w = *(const float4*)(W2 + k * 64 + f0);
    acc0.x = fmaf(h.x, w.x, acc0.x); acc0.y = fmaf(h.x, w.y, acc0.y);
    acc0.z = fmaf(h.x, w.z, acc0.z); acc0.w = fmaf(h.x, w.w, acc0.w);
    acc1.x = fmaf(h.y, w.x, acc1.x); acc1.y = fmaf(h.y, w.y, acc1.y);
    acc1.z = fmaf(h.y, w.z, acc1.z); acc1.w = fmaf(h.y, w.w, acc1.w);
    acc2.x = fmaf(h.z, w.x, acc2.x); acc2.y = fmaf(h.z, w.y, acc2.y);
    acc2.z = fmaf(h.z, w.z, acc2.z); acc2.w = fmaf(h.z, w.w, acc2.w);
    acc3.x = fmaf(h.w, w.x, acc3.x); acc3.y = fmaf(h.w, w.y, acc3.y);
    acc3.z = fmaf(h.w, w.z, acc3.z); acc3.w = fmaf(h.w, w.w, acc3.w);
  }
  float4 o;
  if (0 < count - n0) {
    o = make_float4(relu_(acc0.x), relu_(acc0.y), relu_(acc0.z), relu_(acc0.w));
    *(float4*)(xout + (size_t)(base + n0 + 0) * 64 + f0) = o;
  }
  if (1 < count - n0) {
    o = make_float4(relu_(acc1.x), relu_(acc1.y), relu_(acc1.z), relu_(acc1.w));
    *(float4*)(xout + (size_t)(base + n0 + 1) * 64 + f0) = o;
  }
  if (2 < count - n0) {
    o = make_float4(relu_(acc2.x), relu_(acc2.y), relu_(acc2.z), relu_(acc2.w));
    *(float4*)(xout + (size_t)(base + n0 + 2) * 64 + f0) = o;
  }
  if (3 < count - n0) {
    o = make_float4(relu_(acc3.x), relu_(acc3.y), relu_(acc3.z), relu_(acc3.w));
    *(float4*)(xout + (size_t)(base + n0 + 3) * 64 + f0) = o;
  }
}

// ---------------------------------------------------------------------------
// Batch boundaries from the SORTED batch array (no atomics).
// ---------------------------------------------------------------------------
__global__ __launch_bounds__(256) void batch_bounds_dual(
    const int* __restrict__ bat_s, const int* __restrict__ bat_g,
    int* __restrict__ start_s, int* __restrict__ start_g) {
  int half = blockIdx.x >= 391;
  const int* bat = half ? bat_g : bat_s;
  int* start = half ? start_g : start_s;
  int i = (blockIdx.x - half * 391) * 256 + threadIdx.x;
  if (i >= NN) return;
  int cur = bat[i];
  int prev = (i == 0) ? -1 : bat[i - 1];
  for (int b = prev + 1; b <= cur; ++b) start[b] = i;
  if (i == NN - 1) {
    for (int b = cur + 1; b <= NBAT; ++b) start[b] = NN;
  }
}

__global__ __launch_bounds__(256) void pool_mean(
    const float* __restrict__ x2, const int* __restrict__ start, float* __restrict__ pool) {
  __shared__ float s[4][64];
  int g = blockIdx.x;
  int f = threadIdx.x & 63, c = threadIdx.x >> 6;
  int beg = start[g], end = start[g + 1];
  float acc = 0.0f;
  for (int n = beg + c; n < end; n += 4) acc += x2[(size_t)n * 64 + f];
  s[c][f] = acc;
  __syncthreads();
  if (c == 0) {
    float tot = s[0][f] + s[1][f] + s[2][f] + s[3][f];
    float m = (float)(end - beg);
    pool[g * 64 + f] = tot / fmaxf(m, 1.0f);
  }
}

// ---------------------------------------------------------------------------
// regressor: out[b] = relu([s|g|depth] @ rW1 + rb1) @ rW2 + rb2
// ---------------------------------------------------------------------------
__global__ __launch_bounds__(256) void regressor16(
    const float* __restrict__ ps, const float* __restrict__ pg, const float* __restrict__ depth,
    const float* __restrict__ W1, const float* __restrict__ b1,
    const float* __restrict__ W2, const float* __restrict__ b2,
    float* __restrict__ out) {
  __shared__ float zs[16][132];   // [row][k], k in [0,129)
  __shared__ float ys[64][17];
  int base = blockIdx.x * 16;     // grid 32 blocks x 16 rows = 512 exact
  for (int i = threadIdx.x; i < 16 * 64; i += 256) {
    int ln = i >> 6, k = i & 63;
    zs[ln][k]      = ps[(size_t)(base + ln) * 64 + k];
    zs[ln][64 + k] = pg[(size_t)(base + ln) * 64 + k];
  }
  if (threadIdx.x < 16) zs[threadIdx.x][128] = depth[base + threadIdx.x];
  __syncthreads();
  int g = threadIdx.x >> 4;
  int j = threadIdx.x & 15;
  int f0 = j * 4;
  float a0, a1, a2, a3;
  {
    const float4 b = *(const float4*)(b1 + f0);
    a0 = b.x; a1 = b.y; a2 = b.z; a3 = b.w;
  }
  for (int k = 0; k < 129; ++k) {
    float zv = zs[g][k];
    const float4 w = *(const float4*)(W1 + k * 64 + f0);
    a0 = fmaf(zv, w.x, a0); a1 = fmaf(zv, w.y, a1);
    a2 = fmaf(zv, w.z, a2); a3 = fmaf(zv, w.w, a3);
  }
  ys[f0 + 0][g] = relu_(a0);
  ys[f0 + 1][g] = relu_(a1);
  ys[f0 + 2][g] = relu_(a2);
  ys[f0 + 3][g] = relu_(a3);
  __syncthreads();
  float s = ys[f0 + 0][g] * W2[f0 + 0] + ys[f0 + 1][g] * W2[f0 + 1] +
            ys[f0 + 2][g] * W2[f0 + 2] + ys[f0 + 3][g] * W2[f0 + 3];
#pragma unroll
  for (int m = 1; m < 16; m <<= 1) s += __shfl_xor(s, m);
  if (j == 0) out[base + g] = s + b2[0];
}

}  // namespace

extern "C" void kernel_launch(void* const* d_in, const int* in_sizes, int n_in,
                              void* d_out, int out_size, void* d_ws, size_t ws_size,
                              hipStream_t stream) {
  const int*   names_s = (const int*)d_in[0];
  const int*   ei_s    = (const int*)d_in[1];
  const float* ea_s    = (const float*)d_in[2];
  const int*   bat_s   = (const int*)d_in[3];
  const int*   names_g = (const int*)d_in[4];
  const int*   ei_g    = (const int*)d_in[5];
  const float* ea_g    = (const float*)d_in[6];
  const int*   bat_g   = (const int*)d_in[7];
  const float* depth   = (const float*)d_in[8];
  const float* idW1 = (const float*)d_in[9],  *idb1 = (const float*)d_in[10];
  const float* idW2 = (const float*)d_in[11], *idb2 = (const float*)d_in[12];
  const float* edW1 = (const float*)d_in[13], *edb1 = (const float*)d_in[14];
  const float* edW2 = (const float*)d_in[15], *edb2 = (const float*)d_in[16];
  const float* s1W1 = (const float*)d_in[17], *s1b1 = (const float*)d_in[18];
  const float* s1W2 = (const float*)d_in[19], *s1b2 = (const float*)d_in[20];
  const float* s2W1 = (const float*)d_in[21], *s2b1 = (const float*)d_in[22];
  const float* s2W2 = (const float*)d_in[23], *s2b2 = (const float*)d_in[24];
  const float* s2LW = (const float*)d_in[25], *s2Lb = (const float*)d_in[26];
  const float* g1W1 = (const float*)d_in[27], *g1b1 = (const float*)d_in[28];
  const float* g1W2 = (const float*)d_in[29], *g1b2 = (const float*)d_in[30];
  const float* g2W1 = (const float*)d_in[31], *g2b1 = (const float*)d_in[32];
  const float* g2W2 = (const float*)d_in[33], *g2b2 = (const float*)d_in[34];
  const float* g2LW = (const float*)d_in[35], *g2Lb = (const float*)d_in[36];
  const float* rW1  = (const float*)d_in[37], *rb1  = (const float*)d_in[38];
  const float* rW2  = (const float*)d_in[39], *rb2  = (const float*)d_in[40];
  (void)in_sizes; (void)n_in; (void)out_size; (void)ws_size;

  char* ws = (char*)d_ws;
  size_t off = 0;
  auto alloc = [&](size_t bytes) -> char* {
    char* p = ws + off;
    off += (bytes + 255) & ~(size_t)255;
    return p;
  };
  float* tabs    = (float*)alloc((size_t)TAB_TOTAL * 4);
  // bufA/bufB (51.2 MB) alias the partition scratch: part[] is fully
  // consumed by partition_to_csr before node_embed writes bufA.
  char*  bigreg  = alloc((size_t)2 * NN * 64 * 4);          // 51,200,000 B
  float* bufA    = (float*)bigreg;
  float* bufB    = (float*)(bigreg + (size_t)NN * 64 * 4);
  int2*  part    = (int2*)bigreg;                           // TE*8 = 25.6 MB
  int2*  colattr = (int2*) alloc((size_t)TE * 8);           // final CSR order
  int*   ccnt    = (int*)  alloc((size_t)NC * 4);
  int*   cbase   = (int*)  alloc((size_t)NC * 4);
  int*   gcur    = (int*)  alloc((size_t)NC * 4);
  int*   rowptr  = (int*)  alloc((size_t)(2 * NN + 1) * 4);
  int*   start_s = (int*)  alloc((size_t)(NBAT + 1) * 4);
  int*   start_g = (int*)  alloc((size_t)(NBAT + 1) * 4);
  float* pool_s  = (float*)alloc((size_t)NBAT * 64 * 4);
  float* pool_g  = (float*)alloc((size_t)NBAT * 64 * 4);

  build_tables<<<1, 256, 0, stream>>>(edW1, edb1, edW2, edb2, s2LW, s2Lb, g2LW, g2Lb, tabs);

  // --- dense-write CSR build for BOTH graphs
  hipMemsetAsync(ccnt, 0, (size_t)NC * 4, stream);
  coarse_hist<<<ABLK, 256, 0, stream>>>(ei_s + NEDG, ei_g + NEDG, ccnt);
  coarse_scan<<<1, 1024, 0, stream>>>(ccnt, cbase, gcur, rowptr);
  coarse_partition<<<ABLK, 256, 0, stream>>>(ei_s, ei_s + NEDG, ea_s,
                                             ei_g, ei_g + NEDG, ea_g,
                                             gcur, part);
  partition_to_csr<<<NC, 256, 0, stream>>>(ccnt, cbase, part, tabs, rowptr, colattr);
  batch_bounds_dual<<<782, 256, 0, stream>>>(bat_s, bat_g, start_s, start_g);

  auto encoder = [&](const int* names, const int* start, const int* rp,
                     const float* c1W1, const float* c1b1, const float* c1W2, const float* c1b2,
                     const float* c2W1, const float* c2b1, const float* c2W2, const float* c2b2,
                     int enc, float* pool) {
    node_embed<<<391, 256, 0, stream>>>(names, idW1, idb1, idW2, idb2, bufA);
    conv1_agg<<<NN / 4, 256, 0, stream>>>(bufA, rp, colattr, tabs, bufB);
    node_mlp_tile<32><<<(NN + 63) / 64, 256, 0, stream>>>(bufB, c1W1, c1b1, c1W2, c1b2, bufA);
    conv2_agg<<<NN / 4, 256, 0, stream>>>(bufA, rp, colattr, tabs, enc, bufB);
    node_mlp_tile<64><<<(NN + 63) / 64, 256, 0, stream>>>(bufB, c2W1, c2b1, c2W2, c2b2, bufA);
    pool_mean<<<NBAT, 256, 0, stream>>>(bufA, start, pool);
  };

  encoder(names_s, start_s, rowptr,      s1W1, s1b1, s1W2, s1b2, s2W1, s2b1, s2W2, s2b2, 0, pool_s);
  encoder(names_g, start_g, rowptr + NN, g1W1, g1b1, g1W2, g1b2, g2W1, g2b1, g2W2, g2b2, 1, pool_g);

  regressor16<<<32, 256, 0, stream>>>(pool_s, pool_g, depth, rW1, rb1, rW2, rb2, (float*)d_out);
}